// Round 1
// baseline (562.651 us; speedup 1.0000x reference)
//
#include <hip/hip_runtime.h>
#include <hip/hip_bf16.h>

// ContextAwareContrastiveEmbeddingGenerator — MI355X implementation.
// Key structure: only EXISTING rows need k,v; only MISSING rows need q and
// attn_out, and q for missing rows is batch-independent (missing_table).
// Big GEMMs run compacted (≈half the rows) in bf16 MFMA; everything that
// reaches the output exactly (existing cls rows, doc mean, pred head) stays fp32.

typedef unsigned short u16;
typedef unsigned int u32;
typedef __attribute__((ext_vector_type(8))) short sh8;    // 8 x bf16 (4 VGPR)
typedef __attribute__((ext_vector_type(4))) float f32x4;  // MFMA acc

#define BB 2048
#define SS 23
#define DD 768
#define HH 8
#define HDIM 96
#define LL 50
#define NCAP 26624      // 208*128 row cap for compacted rows (23552 expected, +28 sigma)
#define MTILES 208

__device__ __forceinline__ u16 f2bf(float f) {
  u32 u = __float_as_uint(f);
  u32 r = (u + 0x7fffu + ((u >> 16) & 1u)) >> 16;   // RNE
  return (u16)r;
}
__device__ __forceinline__ float bf2f(u16 h) {
  return __uint_as_float(((u32)h) << 16);
}

__device__ __forceinline__ void gld16(const void* g, void* l) {
  __builtin_amdgcn_global_load_lds((const __attribute__((address_space(1))) void*)g,
                                   (__attribute__((address_space(3))) void*)l, 16, 0, 0);
}

// ---------------- Kernel A: per-batch existing-count prefix scan ----------------
__global__ __launch_bounds__(1024) void scan_kernel(const int* __restrict__ exist,
                                                    int* __restrict__ ex_off,
                                                    int* __restrict__ mi_off) {
  __shared__ int buf[2][BB];
  const int t = threadIdx.x;
  for (int b = t; b < BB; b += 1024) {
    int c = 0;
    for (int s = 0; s < SS; ++s) c += (exist[b * SS + s] != 0);
    buf[0][b] = c;
  }
  __syncthreads();
  int src = 0;
  for (int off = 1; off < BB; off <<= 1) {
    for (int b = t; b < BB; b += 1024) {
      int v = buf[src][b];
      if (b >= off) v += buf[src][b - off];
      buf[src ^ 1][b] = v;
    }
    __syncthreads();
    src ^= 1;
  }
  for (int b = t; b < BB; b += 1024) {
    int inc = buf[src][b];               // inclusive prefix of nE
    ex_off[b + 1] = inc;
    mi_off[b + 1] = SS * (b + 1) - inc;
  }
  if (t == 0) { ex_off[0] = 0; mi_off[0] = 0; }
}

// ---------------- Kernel W1/W2: fp32 -> bf16 weight cast ----------------
__global__ void cast_bf16_kernel(const float* __restrict__ src, u16* __restrict__ dst, int n) {
  int i = (blockIdx.x * 256 + threadIdx.x) * 8;
  if (i >= n) return;
  float4 a = *(const float4*)(src + i);
  float4 b = *(const float4*)(src + i + 4);
  uint4 o;
  o.x = (u32)f2bf(a.x) | ((u32)f2bf(a.y) << 16);
  o.y = (u32)f2bf(a.z) | ((u32)f2bf(a.w) << 16);
  o.z = (u32)f2bf(b.x) | ((u32)f2bf(b.y) << 16);
  o.w = (u32)f2bf(b.z) | ((u32)f2bf(b.w) << 16);
  *(uint4*)(dst + i) = o;
}

// ---------------- Kernel W3: q for missing sections (batch-independent, fp32) ----------------
// qm[s, o] = (missing_table[s] . Wq[o] + bq[o]) / sqrt(96)
__global__ void qmiss_kernel(const float* __restrict__ mt, const float* __restrict__ inw,
                             const float* __restrict__ inb, float* __restrict__ qm) {
  const int s = blockIdx.x / 3;
  const int o = (blockIdx.x % 3) * 256 + threadIdx.x;
  const float* mrow = mt + s * DD;
  const float* wrow = inw + (size_t)o * DD;   // q rows are in_proj_w[0:768]
  float acc = 0.f;
  for (int d = 0; d < DD; d += 4) {
    float4 a = *(const float4*)(mrow + d);
    float4 b = *(const float4*)(wrow + d);
    acc += a.x * b.x + a.y * b.y + a.z * b.z + a.w * b.w;
  }
  qm[s * DD + o] = (acc + inb[o]) * 0.10206207261596575f;   // 1/sqrt(96)
}

// ---------------- Kernel B: gather existing rows -> bf16, per-batch fp32 cls sum ----------------
__global__ __launch_bounds__(256) void gather_kernel(const float* __restrict__ cls,
                                                     const int* __restrict__ exist,
                                                     const int* __restrict__ ex_off,
                                                     u16* __restrict__ Xex,
                                                     float* __restrict__ doc_acc) {
  const int b = blockIdx.x, t = threadIdx.x;
  __shared__ int exl[SS];
  __shared__ int nE_s;
  if (t == 0) {
    int n = 0;
    for (int s = 0; s < SS; ++s) if (exist[b * SS + s]) exl[n++] = s;
    nE_s = n;
  }
  __syncthreads();
  const int nE = nE_s;
  const int e0 = ex_off[b];
  float a0 = 0.f, a1 = 0.f, a2 = 0.f;
  for (int i = 0; i < nE; ++i) {
    const float* row = cls + (size_t)(b * SS + exl[i]) * DD;
    float v0 = row[t], v1 = row[t + 256], v2 = row[t + 512];
    a0 += v0; a1 += v1; a2 += v2;
    if (e0 + i < NCAP) {
      u16* xr = Xex + (size_t)(e0 + i) * DD;
      xr[t] = f2bf(v0); xr[t + 256] = f2bf(v1); xr[t + 512] = f2bf(v2);
    }
  }
  float* da = doc_acc + (size_t)b * DD;
  da[t] = a0; da[t + 256] = a1; da[t + 512] = a2;
}

// ---------------- GEMM: out[m,n] = sum_k A[m,k]*Bw[n,k] + bias[n]  (bf16 in, bf16 out) ----------------
// m97-style: 128x128 tile, BK=64, 4 waves (2x2), 4x4 16x16x32 MFMA frags per wave.
__global__ __launch_bounds__(256, 2)
void gemm_bt_kernel(const u16* __restrict__ A, const u16* __restrict__ Bw,
                    const float* __restrict__ bias, u16* __restrict__ Cc,
                    const int* __restrict__ rows_ptr, int N) {
  constexpr int K = 768;
  __shared__ u16 lA[128 * 64];
  __shared__ u16 lB[128 * 64];
  const int m0 = blockIdx.x * 128;
  if (m0 >= rows_ptr[0]) return;   // rows beyond compacted count: skip
  const int n0 = blockIdx.y * 128;
  const int t = threadIdx.x;
  const int w = t >> 6, l = t & 63;
  const int wr = (w >> 1) * 64, wc = (w & 1) * 64;
  const int r16 = l & 15, kg = l >> 4;

  f32x4 acc[4][4] = {};

  const int srow = t >> 3;            // 0..31
  const int scol = (t & 7) * 8;       // 0..56
  const u16* gA = A + (size_t)(m0 + srow) * K + scol;
  const u16* gB = Bw + (size_t)(n0 + srow) * K + scol;
  u16* lAp = lA + t * 8;
  u16* lBp = lB + t * 8;

  for (int kt = 0; kt < K; kt += 64) {
#pragma unroll
    for (int i = 0; i < 4; ++i) {
      gld16(gA + (size_t)i * 32 * K + kt, lAp + i * 2048);
      gld16(gB + (size_t)i * 32 * K + kt, lBp + i * 2048);
    }
    __syncthreads();
#pragma unroll
    for (int kk = 0; kk < 2; ++kk) {
      sh8 af[4], bfr[4];
      const int kc = kk * 32 + kg * 8;
#pragma unroll
      for (int m = 0; m < 4; ++m) af[m] = *(const sh8*)(lA + (wr + m * 16 + r16) * 64 + kc);
#pragma unroll
      for (int n = 0; n < 4; ++n) bfr[n] = *(const sh8*)(lB + (wc + n * 16 + r16) * 64 + kc);
#pragma unroll
      for (int m = 0; m < 4; ++m)
#pragma unroll
        for (int n = 0; n < 4; ++n)
          acc[m][n] = __builtin_amdgcn_mfma_f32_16x16x32_bf16(af[m], bfr[n], acc[m][n], 0, 0, 0);
    }
    __syncthreads();
  }

#pragma unroll
  for (int m = 0; m < 4; ++m) {
    const int row0 = m0 + wr + m * 16 + kg * 4;
#pragma unroll
    for (int n = 0; n < 4; ++n) {
      const int col = n0 + wc + n * 16 + r16;
      const float bv = bias[col];
#pragma unroll
      for (int j = 0; j < 4; ++j)
        Cc[(size_t)(row0 + j) * N + col] = f2bf(acc[m][n][j] + bv);
    }
  }
}

// ---------------- Kernel D: per-batch attention (fp32 softmax, bf16 inputs) ----------------
__global__ __launch_bounds__(512) void attn_kernel(const u16* __restrict__ KV,
                                                   const float* __restrict__ qm,
                                                   const int* __restrict__ exist,
                                                   const int* __restrict__ ex_off,
                                                   const int* __restrict__ mi_off,
                                                   u16* __restrict__ ctx) {
  const int b = blockIdx.x, t = threadIdx.x;
  __shared__ u16 kvL[SS * 1536];        // k: [e][0:768], v: [e][768:1536]
  __shared__ u16 qmL[SS * DD];          // compacted missing q rows (bf16)
  __shared__ float sc[SS * HH * SS];    // [i][h][e]
  __shared__ int exl[SS], mil[SS], cnts[2];
  if (t == 0) {
    int ne = 0, nm = 0;
    for (int s = 0; s < SS; ++s) {
      if (exist[b * SS + s]) exl[ne++] = s; else mil[nm++] = s;
    }
    cnts[0] = ne; cnts[1] = nm;
  }
  __syncthreads();
  const int nE = cnts[0], nM = cnts[1];
  if (nE == 0 || nM == 0) return;

  const int e0 = ex_off[b];
  const int total = nE * 1536;
  const u16* src = KV + (size_t)e0 * 1536;
  for (int i = t * 8; i < total; i += 512 * 8)
    *(sh8*)(kvL + i) = *(const sh8*)(src + i);
  for (int i = t; i < nM * DD; i += 512) {
    int r = i / DD, d = i - r * DD;
    qmL[i] = f2bf(qm[mil[r] * DD + d]);
  }
  __syncthreads();

  // scores[i,h,e] = qm[i,h*96:...] . k[e,h*96:...]
  const int ntask = nM * HH * nE;
  for (int task = t; task < ntask; task += 512) {
    const int e = task % nE;
    const int rem = task / nE;
    const int h = rem % HH;
    const int i = rem / HH;
    const u16* qp = qmL + i * DD + h * HDIM;
    const u16* kp = kvL + e * 1536 + h * HDIM;
    float acc = 0.f;
#pragma unroll
    for (int j0 = 0; j0 < HDIM; j0 += 8) {
      sh8 qv = *(const sh8*)(qp + j0);
      sh8 kv = *(const sh8*)(kp + j0);
#pragma unroll
      for (int j = 0; j < 8; ++j)
        acc += bf2f((u16)qv[j]) * bf2f((u16)kv[j]);
    }
    sc[(i * HH + h) * SS + e] = acc;
  }
  __syncthreads();

  // softmax over e per (i,h)
  for (int r = t; r < nM * HH; r += 512) {
    float* row = sc + r * SS;
    float mx = row[0];
    for (int e = 1; e < nE; ++e) mx = fmaxf(mx, row[e]);
    float sum = 0.f;
    for (int e = 0; e < nE; ++e) { float p = __expf(row[e] - mx); row[e] = p; sum += p; }
    float inv = 1.f / sum;
    for (int e = 0; e < nE; ++e) row[e] *= inv;
  }
  __syncthreads();

  // ctx[i,d] = sum_e attn[i,h(d),e] * v[e,d]
  const int m0 = mi_off[b];
  for (int task = t; task < nM * DD; task += 512) {
    const int i = task / DD, d = task - i * DD;
    const int h = d / HDIM;
    const float* arow = sc + (i * HH + h) * SS;
    float acc = 0.f;
    for (int e = 0; e < nE; ++e)
      acc += arow[e] * bf2f(kvL[e * 1536 + DD + d]);
    if (m0 + i < NCAP)
      ctx[(size_t)(m0 + i) * DD + d] = f2bf(acc);
  }
}

// ---------------- Kernel F: doc mean + prediction head (fp32) ----------------
__global__ __launch_bounds__(256) void final_kernel(const float* __restrict__ doc_acc,
                                                    const u16* __restrict__ AO,
                                                    const int* __restrict__ ex_off,
                                                    const int* __restrict__ mi_off,
                                                    const float* __restrict__ mt,
                                                    const float* __restrict__ pw,
                                                    const float* __restrict__ pb,
                                                    float* __restrict__ out) {
  const int b = blockIdx.x, t = threadIdx.x;
  __shared__ float docL[DD];
  const int nE = ex_off[b + 1] - ex_off[b];
  const int nM = SS - nE;
  if (nE > 0) {
    const int m0 = mi_off[b];
    for (int d = t; d < DD; d += 256) {
      float acc = doc_acc[(size_t)b * DD + d];
      for (int i = 0; i < nM; ++i)
        if (m0 + i < NCAP) acc += bf2f(AO[(size_t)(m0 + i) * DD + d]);
      docL[d] = acc * (1.f / 23.f);
    }
  } else {
    // no existing sections: section_embeddings == missing_table for all s
    for (int d = t; d < DD; d += 256) {
      float acc = 0.f;
      for (int s = 0; s < SS; ++s) acc += mt[s * DD + d];
      docL[d] = acc * (1.f / 23.f);
    }
  }
  __syncthreads();
  if (t < LL) {
    const float* wr = pw + (size_t)t * DD;
    float acc = 0.f;
    for (int d = 0; d < DD; d += 4) {
      float4 wv = *(const float4*)(wr + d);
      acc += docL[d] * wv.x + docL[d + 1] * wv.y + docL[d + 2] * wv.z + docL[d + 3] * wv.w;
    }
    out[(size_t)b * LL + t] = acc + pb[t];
  }
}

extern "C" void kernel_launch(void* const* d_in, const int* in_sizes, int n_in,
                              void* d_out, int out_size, void* d_ws, size_t ws_size,
                              hipStream_t stream) {
  const float* cls  = (const float*)d_in[0];
  const int*   exm  = (const int*)d_in[1];
  const float* mt   = (const float*)d_in[2];
  const float* inw  = (const float*)d_in[3];
  const float* inb  = (const float*)d_in[4];
  const float* outw = (const float*)d_in[5];
  const float* outb = (const float*)d_in[6];
  const float* pw   = (const float*)d_in[7];
  const float* pb   = (const float*)d_in[8];
  float* out = (float*)d_out;

  char* ws = (char*)d_ws;
  size_t off = 0;
  auto alloc = [&](size_t bytes) {
    size_t cur = (off + 255) & ~(size_t)255;
    off = cur + bytes;
    return ws + cur;
  };
  int*   ex_off  = (int*)alloc((BB + 1) * sizeof(int));
  int*   mi_off  = (int*)alloc((BB + 1) * sizeof(int));
  u16*   wkv     = (u16*)alloc((size_t)1536 * DD * 2);
  u16*   wout    = (u16*)alloc((size_t)DD * DD * 2);
  float* qm      = (float*)alloc((size_t)SS * DD * 4);
  float* doc_acc = (float*)alloc((size_t)BB * DD * 4);
  u16*   Xex     = (u16*)alloc((size_t)NCAP * DD * 2);     // later reused as ctx
  u16*   KV      = (u16*)alloc((size_t)NCAP * 1536 * 2);   // later reused as AO
  u16*   ctx = Xex;   // Xex dead after KV GEMM
  u16*   AO  = KV;    // KV dead after attention

  scan_kernel<<<1, 1024, 0, stream>>>(exm, ex_off, mi_off);
  cast_bf16_kernel<<<(1536 * DD / 8 + 255) / 256, 256, 0, stream>>>(inw + (size_t)DD * DD, wkv, 1536 * DD);
  cast_bf16_kernel<<<(DD * DD / 8 + 255) / 256, 256, 0, stream>>>(outw, wout, DD * DD);
  qmiss_kernel<<<SS * 3, 256, 0, stream>>>(mt, inw, inb, qm);
  gather_kernel<<<BB, 256, 0, stream>>>(cls, exm, ex_off, Xex, doc_acc);
  gemm_bt_kernel<<<dim3(MTILES, 12), 256, 0, stream>>>(Xex, wkv, inb + DD, KV, ex_off + BB, 1536);
  attn_kernel<<<BB, 512, 0, stream>>>(KV, qm, exm, ex_off, mi_off, ctx);
  gemm_bt_kernel<<<dim3(MTILES, 6), 256, 0, stream>>>(ctx, wout, outb, AO, mi_off + BB, 768);
  final_kernel<<<BB, 256, 0, stream>>>(doc_acc, AO, ex_off, mi_off, mt, pw, pb, out);
}

// Round 2
// 536.879 us; speedup vs baseline: 1.0480x; 1.0480x over previous
//
#include <hip/hip_runtime.h>
#include <hip/hip_bf16.h>

// ContextAwareContrastiveEmbeddingGenerator — MI355X implementation (round 2).
// Round-2 changes vs round 1:
//  * attn_kernel rewritten: K staged in LDS with per-head-padded layout
//    kL[e][h][104] (head slots start at distinct bank groups -> conflict-free
//    b128 reads); q (batch-invariant, bf16-precomputed) and v read from
//    global (L1/L2); score matrix padded to stride 25. LDS 123 KB -> 57 KB.
//  * GEMM grid axes swapped (N-tile on blockIdx.x) so blocks sharing an
//    A-tile are dispatch-adjacent -> A read ~once from HBM, B L2-resident.
//  * qmiss writes bf16 directly.

typedef unsigned short u16;
typedef unsigned int u32;
typedef __attribute__((ext_vector_type(8))) short sh8;    // 8 x bf16 (4 VGPR)
typedef __attribute__((ext_vector_type(4))) float f32x4;  // MFMA acc

#define BB 2048
#define SS 23
#define DD 768
#define HH 8
#define HDIM 96
#define LL 50
#define NCAP 26624      // 208*128 row cap for compacted rows (23552 expected, +28 sigma)
#define MTILES 208

__device__ __forceinline__ u16 f2bf(float f) {
  u32 u = __float_as_uint(f);
  u32 r = (u + 0x7fffu + ((u >> 16) & 1u)) >> 16;   // RNE
  return (u16)r;
}
__device__ __forceinline__ float bf2f(u16 h) {
  return __uint_as_float(((u32)h) << 16);
}

__device__ __forceinline__ void gld16(const void* g, void* l) {
  __builtin_amdgcn_global_load_lds((const __attribute__((address_space(1))) void*)g,
                                   (__attribute__((address_space(3))) void*)l, 16, 0, 0);
}

// ---------------- Kernel A: per-batch existing-count prefix scan ----------------
__global__ __launch_bounds__(1024) void scan_kernel(const int* __restrict__ exist,
                                                    int* __restrict__ ex_off,
                                                    int* __restrict__ mi_off) {
  __shared__ int buf[2][BB];
  const int t = threadIdx.x;
  for (int b = t; b < BB; b += 1024) {
    int c = 0;
    for (int s = 0; s < SS; ++s) c += (exist[b * SS + s] != 0);
    buf[0][b] = c;
  }
  __syncthreads();
  int src = 0;
  for (int off = 1; off < BB; off <<= 1) {
    for (int b = t; b < BB; b += 1024) {
      int v = buf[src][b];
      if (b >= off) v += buf[src][b - off];
      buf[src ^ 1][b] = v;
    }
    __syncthreads();
    src ^= 1;
  }
  for (int b = t; b < BB; b += 1024) {
    int inc = buf[src][b];               // inclusive prefix of nE
    ex_off[b + 1] = inc;
    mi_off[b + 1] = SS * (b + 1) - inc;
  }
  if (t == 0) { ex_off[0] = 0; mi_off[0] = 0; }
}

// ---------------- Kernel W1/W2: fp32 -> bf16 weight cast ----------------
__global__ void cast_bf16_kernel(const float* __restrict__ src, u16* __restrict__ dst, int n) {
  int i = (blockIdx.x * 256 + threadIdx.x) * 8;
  if (i >= n) return;
  float4 a = *(const float4*)(src + i);
  float4 b = *(const float4*)(src + i + 4);
  uint4 o;
  o.x = (u32)f2bf(a.x) | ((u32)f2bf(a.y) << 16);
  o.y = (u32)f2bf(a.z) | ((u32)f2bf(a.w) << 16);
  o.z = (u32)f2bf(b.x) | ((u32)f2bf(b.y) << 16);
  o.w = (u32)f2bf(b.z) | ((u32)f2bf(b.w) << 16);
  *(uint4*)(dst + i) = o;
}

// ---------------- Kernel W3: q for missing sections (batch-independent), bf16 out ----------------
// qm[s, o] = (missing_table[s] . Wq[o] + bq[o]) / sqrt(96)
__global__ void qmiss_kernel(const float* __restrict__ mt, const float* __restrict__ inw,
                             const float* __restrict__ inb, u16* __restrict__ qm) {
  const int s = blockIdx.x / 3;
  const int o = (blockIdx.x % 3) * 256 + threadIdx.x;
  const float* mrow = mt + s * DD;
  const float* wrow = inw + (size_t)o * DD;   // q rows are in_proj_w[0:768]
  float acc = 0.f;
  for (int d = 0; d < DD; d += 4) {
    float4 a = *(const float4*)(mrow + d);
    float4 b = *(const float4*)(wrow + d);
    acc += a.x * b.x + a.y * b.y + a.z * b.z + a.w * b.w;
  }
  qm[s * DD + o] = f2bf((acc + inb[o]) * 0.10206207261596575f);   // 1/sqrt(96)
}

// ---------------- Kernel B: gather existing rows -> bf16, per-batch fp32 cls sum ----------------
__global__ __launch_bounds__(256) void gather_kernel(const float* __restrict__ cls,
                                                     const int* __restrict__ exist,
                                                     const int* __restrict__ ex_off,
                                                     u16* __restrict__ Xex,
                                                     float* __restrict__ doc_acc) {
  const int b = blockIdx.x, t = threadIdx.x;
  __shared__ int exl[SS];
  __shared__ int nE_s;
  if (t == 0) {
    int n = 0;
    for (int s = 0; s < SS; ++s) if (exist[b * SS + s]) exl[n++] = s;
    nE_s = n;
  }
  __syncthreads();
  const int nE = nE_s;
  const int e0 = ex_off[b];
  float a0 = 0.f, a1 = 0.f, a2 = 0.f;
  for (int i = 0; i < nE; ++i) {
    const float* row = cls + (size_t)(b * SS + exl[i]) * DD;
    float v0 = row[t], v1 = row[t + 256], v2 = row[t + 512];
    a0 += v0; a1 += v1; a2 += v2;
    if (e0 + i < NCAP) {
      u16* xr = Xex + (size_t)(e0 + i) * DD;
      xr[t] = f2bf(v0); xr[t + 256] = f2bf(v1); xr[t + 512] = f2bf(v2);
    }
  }
  float* da = doc_acc + (size_t)b * DD;
  da[t] = a0; da[t + 256] = a1; da[t + 512] = a2;
}

// ---------------- GEMM: out[m,n] = sum_k A[m,k]*Bw[n,k] + bias[n]  (bf16 in, bf16 out) ----------------
// m97-style: 128x128 tile, BK=64, 4 waves (2x2), 4x4 16x16x32 MFMA frags per wave.
// Grid: (N/128, MTILES) — N-tile on x so A-tile sharers are dispatch-adjacent.
__global__ __launch_bounds__(256, 2)
void gemm_bt_kernel(const u16* __restrict__ A, const u16* __restrict__ Bw,
                    const float* __restrict__ bias, u16* __restrict__ Cc,
                    const int* __restrict__ rows_ptr, int N) {
  constexpr int K = 768;
  __shared__ u16 lA[128 * 64];
  __shared__ u16 lB[128 * 64];
  const int m0 = blockIdx.y * 128;
  if (m0 >= rows_ptr[0]) return;   // rows beyond compacted count: skip
  const int n0 = blockIdx.x * 128;
  const int t = threadIdx.x;
  const int w = t >> 6, l = t & 63;
  const int wr = (w >> 1) * 64, wc = (w & 1) * 64;
  const int r16 = l & 15, kg = l >> 4;

  f32x4 acc[4][4] = {};

  const int srow = t >> 3;            // 0..31
  const int scol = (t & 7) * 8;       // 0..56
  const u16* gA = A + (size_t)(m0 + srow) * K + scol;
  const u16* gB = Bw + (size_t)(n0 + srow) * K + scol;
  u16* lAp = lA + t * 8;
  u16* lBp = lB + t * 8;

  for (int kt = 0; kt < K; kt += 64) {
#pragma unroll
    for (int i = 0; i < 4; ++i) {
      gld16(gA + (size_t)i * 32 * K + kt, lAp + i * 2048);
      gld16(gB + (size_t)i * 32 * K + kt, lBp + i * 2048);
    }
    __syncthreads();
#pragma unroll
    for (int kk = 0; kk < 2; ++kk) {
      sh8 af[4], bfr[4];
      const int kc = kk * 32 + kg * 8;
#pragma unroll
      for (int m = 0; m < 4; ++m) af[m] = *(const sh8*)(lA + (wr + m * 16 + r16) * 64 + kc);
#pragma unroll
      for (int n = 0; n < 4; ++n) bfr[n] = *(const sh8*)(lB + (wc + n * 16 + r16) * 64 + kc);
#pragma unroll
      for (int m = 0; m < 4; ++m)
#pragma unroll
        for (int n = 0; n < 4; ++n)
          acc[m][n] = __builtin_amdgcn_mfma_f32_16x16x32_bf16(af[m], bfr[n], acc[m][n], 0, 0, 0);
    }
    __syncthreads();
  }

#pragma unroll
  for (int m = 0; m < 4; ++m) {
    const int row0 = m0 + wr + m * 16 + kg * 4;
#pragma unroll
    for (int n = 0; n < 4; ++n) {
      const int col = n0 + wc + n * 16 + r16;
      const float bv = bias[col];
#pragma unroll
      for (int j = 0; j < 4; ++j)
        Cc[(size_t)(row0 + j) * N + col] = f2bf(acc[m][n][j] + bv);
    }
  }
}

// ---------------- Kernel D: per-batch attention (fp32 softmax, bf16 inputs) ----------------
// LDS: kL[e][h][104] (head slots at distinct bank groups -> conflict-free b128
// reads), sc padded to stride 25 (coprime 32). q from global (bf16, L2-hot,
// batch-invariant), v from global (contiguous-d coalesced, L1 reuse).
__global__ __launch_bounds__(512, 4) void attn_kernel(const u16* __restrict__ KV,
                                                      const u16* __restrict__ qm,
                                                      const int* __restrict__ exist,
                                                      const int* __restrict__ ex_off,
                                                      const int* __restrict__ mi_off,
                                                      u16* __restrict__ ctx) {
  const int b = blockIdx.x, t = threadIdx.x;
  __shared__ u16 kL[SS][HH][104];       // 38272 B; slot bank starts {0,20,8,28,16,4,24,12}
  __shared__ float sc[SS * HH][25];     // 18400 B; [i*8+h][e]
  __shared__ int mil[SS], cnts[2];
  if (t == 0) {
    int ne = 0, nm = 0;
    for (int s = 0; s < SS; ++s) {
      if (exist[b * SS + s]) ne++; else mil[nm++] = s;
    }
    cnts[0] = ne; cnts[1] = nm;
  }
  __syncthreads();
  const int nE = cnts[0], nM = cnts[1];
  if (nE == 0 || nM == 0) return;

  const int e0 = ex_off[b];
  const int m0 = mi_off[b];

  // stage k -> kL[e][h][0:96], 16B chunks (all offsets 16B-aligned)
  const int nchunk = nE * HH * 12;      // 12 x sh8 per (e,h)
  for (int c = t; c < nchunk; c += 512) {
    const int j = c % 12;
    const int rem = c / 12;
    const int h = rem % HH;
    const int e = rem / HH;
    sh8 val = *(const sh8*)(KV + (size_t)(e0 + e) * 1536 + h * HDIM + j * 8);
    *(sh8*)(&kL[e][h][j * 8]) = val;
  }
  __syncthreads();

  // scores[i,h,e] = q[mil[i],h,:] . k[e,h,:]   (e wave-uniform -> k broadcast over i)
  const int ntask = nE * nM * HH;
  for (int task = t; task < ntask; task += 512) {
    const int h = task & 7;
    const int rem = task >> 3;
    const int i = rem % nM;
    const int e = rem / nM;
    const u16* qp = qm + mil[i] * DD + h * HDIM;
    float acc = 0.f;
#pragma unroll
    for (int j0 = 0; j0 < HDIM; j0 += 8) {
      sh8 qv = *(const sh8*)(qp + j0);
      sh8 kv = *(const sh8*)(&kL[e][h][j0]);
#pragma unroll
      for (int j = 0; j < 8; ++j)
        acc += bf2f((u16)qv[j]) * bf2f((u16)kv[j]);
    }
    sc[i * HH + h][e] = acc;
  }
  __syncthreads();

  // softmax over e per (i,h) row
  for (int r = t; r < nM * HH; r += 512) {
    float* row = sc[r];
    float mx = row[0];
    for (int e = 1; e < nE; ++e) mx = fmaxf(mx, row[e]);
    float sum = 0.f;
    for (int e = 0; e < nE; ++e) { float p = __expf(row[e] - mx); row[e] = p; sum += p; }
    float inv = 1.f / sum;
    for (int e = 0; e < nE; ++e) row[e] *= inv;
  }
  __syncthreads();

  // ctx[i,d] = sum_e attn[i,h(d),e] * v[e,d]; v read coalesced from global (L1 reuse)
  const int ntask2 = nM * DD;
  for (int task = t; task < ntask2; task += 512) {
    const int i = task / DD, d = task - i * DD;
    const int h = d / HDIM;
    const float* arow = sc[i * HH + h];
    const u16* vp = KV + (size_t)e0 * 1536 + DD + d;
    float acc = 0.f;
    for (int e = 0; e < nE; ++e)
      acc += arow[e] * bf2f(vp[(size_t)e * 1536]);
    if (m0 + i < NCAP)
      ctx[(size_t)(m0 + i) * DD + d] = f2bf(acc);
  }
}

// ---------------- Kernel F: doc mean + prediction head (fp32) ----------------
__global__ __launch_bounds__(256) void final_kernel(const float* __restrict__ doc_acc,
                                                    const u16* __restrict__ AO,
                                                    const int* __restrict__ ex_off,
                                                    const int* __restrict__ mi_off,
                                                    const float* __restrict__ mt,
                                                    const float* __restrict__ pw,
                                                    const float* __restrict__ pb,
                                                    float* __restrict__ out) {
  const int b = blockIdx.x, t = threadIdx.x;
  __shared__ float docL[DD];
  const int nE = ex_off[b + 1] - ex_off[b];
  const int nM = SS - nE;
  if (nE > 0) {
    const int m0 = mi_off[b];
    for (int d = t; d < DD; d += 256) {
      float acc = doc_acc[(size_t)b * DD + d];
      for (int i = 0; i < nM; ++i)
        if (m0 + i < NCAP) acc += bf2f(AO[(size_t)(m0 + i) * DD + d]);
      docL[d] = acc * (1.f / 23.f);
    }
  } else {
    // no existing sections: section_embeddings == missing_table for all s
    for (int d = t; d < DD; d += 256) {
      float acc = 0.f;
      for (int s = 0; s < SS; ++s) acc += mt[s * DD + d];
      docL[d] = acc * (1.f / 23.f);
    }
  }
  __syncthreads();
  if (t < LL) {
    const float* wr = pw + (size_t)t * DD;
    float acc = 0.f;
    for (int d = 0; d < DD; d += 4) {
      float4 wv = *(const float4*)(wr + d);
      acc += docL[d] * wv.x + docL[d + 1] * wv.y + docL[d + 2] * wv.z + docL[d + 3] * wv.w;
    }
    out[(size_t)b * LL + t] = acc + pb[t];
  }
}

extern "C" void kernel_launch(void* const* d_in, const int* in_sizes, int n_in,
                              void* d_out, int out_size, void* d_ws, size_t ws_size,
                              hipStream_t stream) {
  const float* cls  = (const float*)d_in[0];
  const int*   exm  = (const int*)d_in[1];
  const float* mt   = (const float*)d_in[2];
  const float* inw  = (const float*)d_in[3];
  const float* inb  = (const float*)d_in[4];
  const float* outw = (const float*)d_in[5];
  const float* outb = (const float*)d_in[6];
  const float* pw   = (const float*)d_in[7];
  const float* pb   = (const float*)d_in[8];
  float* out = (float*)d_out;

  char* ws = (char*)d_ws;
  size_t off = 0;
  auto alloc = [&](size_t bytes) {
    size_t cur = (off + 255) & ~(size_t)255;
    off = cur + bytes;
    return ws + cur;
  };
  int*   ex_off  = (int*)alloc((BB + 1) * sizeof(int));
  int*   mi_off  = (int*)alloc((BB + 1) * sizeof(int));
  u16*   wkv     = (u16*)alloc((size_t)1536 * DD * 2);
  u16*   wout    = (u16*)alloc((size_t)DD * DD * 2);
  u16*   qm      = (u16*)alloc((size_t)SS * DD * 2);
  float* doc_acc = (float*)alloc((size_t)BB * DD * 4);
  u16*   Xex     = (u16*)alloc((size_t)NCAP * DD * 2);     // later reused as ctx
  u16*   KV      = (u16*)alloc((size_t)NCAP * 1536 * 2);   // later reused as AO
  u16*   ctx = Xex;   // Xex dead after KV GEMM
  u16*   AO  = KV;    // KV dead after attention

  scan_kernel<<<1, 1024, 0, stream>>>(exm, ex_off, mi_off);
  cast_bf16_kernel<<<(1536 * DD / 8 + 255) / 256, 256, 0, stream>>>(inw + (size_t)DD * DD, wkv, 1536 * DD);
  cast_bf16_kernel<<<(DD * DD / 8 + 255) / 256, 256, 0, stream>>>(outw, wout, DD * DD);
  qmiss_kernel<<<SS * 3, 256, 0, stream>>>(mt, inw, inb, qm);
  gather_kernel<<<BB, 256, 0, stream>>>(cls, exm, ex_off, Xex, doc_acc);
  gemm_bt_kernel<<<dim3(12, MTILES), 256, 0, stream>>>(Xex, wkv, inb + DD, KV, ex_off + BB, 1536);
  attn_kernel<<<BB, 512, 0, stream>>>(KV, qm, exm, ex_off, mi_off, ctx);
  gemm_bt_kernel<<<dim3(6, MTILES), 256, 0, stream>>>(ctx, wout, outb, AO, mi_off + BB, 768);
  final_kernel<<<BB, 256, 0, stream>>>(doc_acc, AO, ex_off, mi_off, mt, pw, pb, out);
}

// Round 3
// 452.264 us; speedup vs baseline: 1.2441x; 1.1871x over previous
//
#include <hip/hip_runtime.h>
#include <hip/hip_bf16.h>

// ContextAwareContrastiveEmbeddingGenerator — MI355X (round 3).
// Structural collapse: output only needs per-batch SUMS of attn_out over
// missing rows. So:
//   * out_proj folds into Wfold = pw @ out_proj_w  ([50][768], one-time).
//   * PV collapses over i: ctxsum[d] = sum_e (sum_i p[i,h,e]) v[e,d]  (fp32).
//   * scores via g-trick: score[i,h,e] = g[s,h,:].x_e + sbias[s,h] where
//     g = q_miss*Wk is batch-invariant -> k never materialized. S-GEMM (N=184)
//     fused with V-GEMM into one M~23552 x N=1024 x K=768 bf16 MFMA GEMM.

typedef unsigned short u16;
typedef unsigned int u32;
typedef __attribute__((ext_vector_type(8))) short sh8;    // 8 x bf16
typedef __attribute__((ext_vector_type(4))) float f32x4;  // MFMA acc

#define BB 2048
#define SS 23
#define DD 768
#define HH 8
#define HDIM 96
#define LL 50
#define NN 1024         // fused GEMM N: [0,768)=v, [768,952)=scores, rest pad
#define NCAP 26624      // 208*128 row cap (23552 expected, +28 sigma)
#define MTILES 208

__device__ __forceinline__ u16 f2bf(float f) {
  u32 u = __float_as_uint(f);
  u32 r = (u + 0x7fffu + ((u >> 16) & 1u)) >> 16;   // RNE
  return (u16)r;
}
__device__ __forceinline__ float bf2f(u16 h) {
  return __uint_as_float(((u32)h) << 16);
}

__device__ __forceinline__ void gld16(const void* g, void* l) {
  __builtin_amdgcn_global_load_lds((const __attribute__((address_space(1))) void*)g,
                                   (__attribute__((address_space(3))) void*)l, 16, 0, 0);
}

// ---------------- per-batch existing-count prefix scan ----------------
__global__ __launch_bounds__(1024) void scan_kernel(const int* __restrict__ exist,
                                                    int* __restrict__ ex_off) {
  __shared__ int buf[2][BB];
  const int t = threadIdx.x;
  for (int b = t; b < BB; b += 1024) {
    int c = 0;
    for (int s = 0; s < SS; ++s) c += (exist[b * SS + s] != 0);
    buf[0][b] = c;
  }
  __syncthreads();
  int src = 0;
  for (int off = 1; off < BB; off <<= 1) {
    for (int b = t; b < BB; b += 1024) {
      int v = buf[src][b];
      if (b >= off) v += buf[src][b - off];
      buf[src ^ 1][b] = v;
    }
    __syncthreads();
    src ^= 1;
  }
  for (int b = t; b < BB; b += 1024) ex_off[b + 1] = buf[src][b];
  if (t == 0) ex_off[0] = 0;
}

// ---------------- fp32 -> bf16 cast (Wv -> Bcomb rows [0,768)) ----------------
__global__ void cast_bf16_kernel(const float* __restrict__ src, u16* __restrict__ dst, int n) {
  int i = (blockIdx.x * 256 + threadIdx.x) * 8;
  if (i >= n) return;
  float4 a = *(const float4*)(src + i);
  float4 b = *(const float4*)(src + i + 4);
  uint4 o;
  o.x = (u32)f2bf(a.x) | ((u32)f2bf(a.y) << 16);
  o.y = (u32)f2bf(a.z) | ((u32)f2bf(a.w) << 16);
  o.z = (u32)f2bf(b.x) | ((u32)f2bf(b.y) << 16);
  o.w = (u32)f2bf(b.z) | ((u32)f2bf(b.w) << 16);
  *(uint4*)(dst + i) = o;
}

// ---------------- q rows for all 23 sections (fp32, scaled) ----------------
__global__ void qmiss_kernel(const float* __restrict__ mt, const float* __restrict__ inw,
                             const float* __restrict__ inb, float* __restrict__ qmf) {
  const int s = blockIdx.x / 3;
  const int o = (blockIdx.x % 3) * 256 + threadIdx.x;
  const float* mrow = mt + s * DD;
  const float* wrow = inw + (size_t)o * DD;   // q rows: in_proj_w[0:768]
  float acc = 0.f;
  for (int d = 0; d < DD; d += 4) {
    float4 a = *(const float4*)(mrow + d);
    float4 b = *(const float4*)(wrow + d);
    acc += a.x * b.x + a.y * b.y + a.z * b.z + a.w * b.w;
  }
  qmf[s * DD + o] = (acc + inb[o]) * 0.10206207261596575f;   // 1/sqrt(96)
}

// ---------------- bias prep: biasc[0:768)=v-bias, [952:1024)=0 ----------------
__global__ void prepb_kernel(const float* __restrict__ inb, float* __restrict__ biasc) {
  int t = blockIdx.x * 256 + threadIdx.x;
  if (t < 768) biasc[t] = inb[1536 + t];
  else if (t >= 952 && t < 1024) biasc[t] = 0.f;
}

// ---------------- g rows: g[s*8+h][D] = sum_d q[s,h,d]*Wk[h*96+d][D]; sbias ----------------
__global__ void gk_kernel(const float* __restrict__ qmf, const float* __restrict__ inw,
                          const float* __restrict__ inb, u16* __restrict__ Bcomb,
                          float* __restrict__ biasc) {
  const int r = blockIdx.y;            // 0..183
  const int s = r >> 3, h = r & 7;
  const int Dc = blockIdx.x * 256 + threadIdx.x;
  const float* q = qmf + s * DD + h * HDIM;
  const float* wk = inw + (size_t)(DD + h * HDIM) * DD + Dc;   // k rows: [768,1536)
  float acc = 0.f;
  for (int d = 0; d < HDIM; ++d)
    acc += q[d] * wk[(size_t)d * DD];
  Bcomb[(size_t)(DD + r) * DD + Dc] = f2bf(acc);
  if (blockIdx.x == 0 && threadIdx.x == 0) {
    float bb = 0.f;
    const float* bk = inb + DD + h * HDIM;
    for (int d = 0; d < HDIM; ++d) bb += q[d] * bk[d];
    biasc[DD + r] = bb;
  }
}

// ---------------- mtmean[d] = mean_s missing_table[s][d] ----------------
__global__ void mtmean_kernel(const float* __restrict__ mt, float* __restrict__ mtm) {
  const int d = threadIdx.x;   // 768 threads
  float acc = 0.f;
  for (int s = 0; s < SS; ++s) acc += mt[s * DD + d];
  mtm[d] = acc * (1.f / 23.f);
}

// ---------------- Wfold[l][din] = sum_dout pw[l][dout]*Wout[dout][din]; boutdot, logits0 ----------------
__global__ __launch_bounds__(256) void wfold_kernel(const float* __restrict__ pw,
                                                    const float* __restrict__ outw,
                                                    const float* __restrict__ outb,
                                                    const float* __restrict__ pb,
                                                    const float* __restrict__ mtm,
                                                    float* __restrict__ Wfold,
                                                    float* __restrict__ boutdot,
                                                    float* __restrict__ logits0) {
  const int l = blockIdx.y;
  const int din = blockIdx.x * 256 + threadIdx.x;
  float acc = 0.f;
  for (int dout = 0; dout < DD; ++dout)
    acc += pw[(size_t)l * DD + dout] * outw[(size_t)dout * DD + din];
  Wfold[(size_t)l * DD + din] = acc;
  if (blockIdx.x == 0) {
    __shared__ float red[2][256];
    const int t = threadIdx.x;
    float pbd = 0.f, plz = 0.f;
    for (int d = t; d < DD; d += 256) {
      float pv = pw[(size_t)l * DD + d];
      pbd += pv * outb[d];
      plz += pv * mtm[d];
    }
    red[0][t] = pbd; red[1][t] = plz;
    __syncthreads();
    for (int s = 128; s > 0; s >>= 1) {
      if (t < s) { red[0][t] += red[0][t + s]; red[1][t] += red[1][t + s]; }
      __syncthreads();
    }
    if (t == 0) { boutdot[l] = red[0][0]; logits0[l] = red[1][0] + pb[l]; }
  }
}

// ---------------- gather existing rows -> bf16, per-batch fp32 cls sum ----------------
__global__ __launch_bounds__(256) void gather_kernel(const float* __restrict__ cls,
                                                     const int* __restrict__ exist,
                                                     const int* __restrict__ ex_off,
                                                     u16* __restrict__ Xex,
                                                     float* __restrict__ doc_acc) {
  const int b = blockIdx.x, t = threadIdx.x;
  __shared__ int exl[SS];
  __shared__ int nE_s;
  if (t == 0) {
    int n = 0;
    for (int s = 0; s < SS; ++s) if (exist[b * SS + s]) exl[n++] = s;
    nE_s = n;
  }
  __syncthreads();
  const int nE = nE_s;
  const int e0 = ex_off[b];
  float a0 = 0.f, a1 = 0.f, a2 = 0.f;
  for (int i = 0; i < nE; ++i) {
    const float* row = cls + (size_t)(b * SS + exl[i]) * DD;
    float v0 = row[t], v1 = row[t + 256], v2 = row[t + 512];
    a0 += v0; a1 += v1; a2 += v2;
    if (e0 + i < NCAP) {
      u16* xr = Xex + (size_t)(e0 + i) * DD;
      xr[t] = f2bf(v0); xr[t + 256] = f2bf(v1); xr[t + 512] = f2bf(v2);
    }
  }
  float* da = doc_acc + (size_t)b * DD;
  da[t] = a0; da[t + 256] = a1; da[t + 512] = a2;
}

// ---------------- GEMM: C[m,n] = sum_k A[m,k]*Bw[n,k] + bias[n]  (bf16->bf16) ----------------
// 128x128 tile, BK=64, 4 waves, 4x4 16x16x32 MFMA frags. Grid (N/128, MTILES).
__global__ __launch_bounds__(256, 2)
void gemm_bt_kernel(const u16* __restrict__ A, const u16* __restrict__ Bw,
                    const float* __restrict__ bias, u16* __restrict__ Cc,
                    const int* __restrict__ rows_ptr, int N) {
  constexpr int K = 768;
  __shared__ u16 lA[128 * 64];
  __shared__ u16 lB[128 * 64];
  const int m0 = blockIdx.y * 128;
  if (m0 >= rows_ptr[0]) return;
  const int n0 = blockIdx.x * 128;
  const int t = threadIdx.x;
  const int w = t >> 6, l = t & 63;
  const int wr = (w >> 1) * 64, wc = (w & 1) * 64;
  const int r16 = l & 15, kg = l >> 4;

  f32x4 acc[4][4] = {};

  const int srow = t >> 3;
  const int scol = (t & 7) * 8;
  const u16* gA = A + (size_t)(m0 + srow) * K + scol;
  const u16* gB = Bw + (size_t)(n0 + srow) * K + scol;
  u16* lAp = lA + t * 8;
  u16* lBp = lB + t * 8;

  for (int kt = 0; kt < K; kt += 64) {
#pragma unroll
    for (int i = 0; i < 4; ++i) {
      gld16(gA + (size_t)i * 32 * K + kt, lAp + i * 2048);
      gld16(gB + (size_t)i * 32 * K + kt, lBp + i * 2048);
    }
    __syncthreads();
#pragma unroll
    for (int kk = 0; kk < 2; ++kk) {
      sh8 af[4], bfr[4];
      const int kc = kk * 32 + kg * 8;
#pragma unroll
      for (int m = 0; m < 4; ++m) af[m] = *(const sh8*)(lA + (wr + m * 16 + r16) * 64 + kc);
#pragma unroll
      for (int n = 0; n < 4; ++n) bfr[n] = *(const sh8*)(lB + (wc + n * 16 + r16) * 64 + kc);
#pragma unroll
      for (int m = 0; m < 4; ++m)
#pragma unroll
        for (int n = 0; n < 4; ++n)
          acc[m][n] = __builtin_amdgcn_mfma_f32_16x16x32_bf16(af[m], bfr[n], acc[m][n], 0, 0, 0);
    }
    __syncthreads();
  }

#pragma unroll
  for (int m = 0; m < 4; ++m) {
    const int row0 = m0 + wr + m * 16 + kg * 4;
#pragma unroll
    for (int n = 0; n < 4; ++n) {
      const int col = n0 + wc + n * 16 + r16;
      const float bv = bias[col];
#pragma unroll
      for (int j = 0; j < 4; ++j)
        Cc[(size_t)(row0 + j) * N + col] = f2bf(acc[m][n][j] + bv);
    }
  }
}

// ---------------- attention v3: softmax + p-sum over i + tiny fp32 PV ----------------
__global__ __launch_bounds__(256) void attn3_kernel(const u16* __restrict__ VS,
                                                    const int* __restrict__ exist,
                                                    const int* __restrict__ ex_off,
                                                    float* __restrict__ ctxsum) {
  const int b = blockIdx.x, t = threadIdx.x;
  __shared__ float sc[SS * HH][25];   // [i*8+h][e], stride 25 (coprime 32)
  __shared__ float psum[HH][25];
  __shared__ int mil[SS], cnts[2];
  if (t == 0) {
    int ne = 0, nm = 0;
    for (int s = 0; s < SS; ++s) {
      if (exist[b * SS + s]) ne++; else mil[nm++] = s;
    }
    cnts[0] = ne; cnts[1] = nm;
  }
  __syncthreads();
  const int nE = cnts[0], nM = cnts[1];
  if (nE == 0 || nM == 0) return;
  const size_t e0 = (size_t)ex_off[b];

  // phase 1: load score slice S[e0+e][768 + mil[i]*8 + h] -> sc[i*8+h][e]
  const int ee = t & 31, ig = t >> 5;   // 8 i-slots per pass
  for (int i0 = 0; i0 < nM; i0 += 8) {
    const int i = i0 + ig;
    if (ee < nE && i < nM) {
      sh8 v = *(const sh8*)(VS + (e0 + ee) * NN + DD + mil[i] * 8);
#pragma unroll
      for (int h = 0; h < HH; ++h) sc[i * HH + h][ee] = bf2f((u16)v[h]);
    }
  }
  __syncthreads();

  // phase 2a: softmax over e, row r = t
  if (t < nM * HH) {
    float* row = sc[t];
    float mx = row[0];
    for (int e = 1; e < nE; ++e) mx = fmaxf(mx, row[e]);
    float sum = 0.f;
    for (int e = 0; e < nE; ++e) { float p = __expf(row[e] - mx); row[e] = p; sum += p; }
    float inv = 1.f / sum;
    for (int e = 0; e < nE; ++e) row[e] *= inv;
  }
  __syncthreads();

  // phase 2b: psum[h][e] = sum_i p[i*8+h][e]
  {
    const int h = t >> 5, e2 = t & 31;
    if (e2 < nE) {
      float a = 0.f;
      for (int i = 0; i < nM; ++i) a += sc[i * HH + h][e2];
      psum[h][e2] = a;
    }
  }
  __syncthreads();

  // phase 3: ctxsum[d] = sum_e psum[h(d)][e] * v[e][d]   (fp32)
  for (int d = t; d < DD; d += 256) {
    const int h = d / HDIM;
    float acc = 0.f;
    for (int e = 0; e < nE; ++e)
      acc += psum[h][e] * bf2f(VS[(e0 + e) * NN + d]);
    ctxsum[(size_t)b * DD + d] = acc;
  }
}

// ---------------- final: logits = (clssum.pw + ctxsum.Wfold + nM*boutdot)/23 + pb ----------------
__global__ __launch_bounds__(256) void final2_kernel(const float* __restrict__ doc_acc,
                                                     const float* __restrict__ ctxsum,
                                                     const int* __restrict__ ex_off,
                                                     const float* __restrict__ pw,
                                                     const float* __restrict__ pb,
                                                     const float* __restrict__ Wfold,
                                                     const float* __restrict__ boutdot,
                                                     const float* __restrict__ logits0,
                                                     float* __restrict__ out) {
  const int b = blockIdx.x, t = threadIdx.x;
  const int nE = ex_off[b + 1] - ex_off[b];
  const int nM = SS - nE;
  if (nE == 0) {
    if (t < LL) out[(size_t)b * LL + t] = logits0[t];
    return;
  }
  const int w = t >> 6, lane = t & 63;
  const float* sb = doc_acc + (size_t)b * DD;
  const float* cb = ctxsum + (size_t)b * DD;
  const int d0 = lane * 12;
  for (int l = w; l < LL; l += 4) {
    const float* pwl = pw + (size_t)l * DD + d0;
    const float* wfl = Wfold + (size_t)l * DD + d0;
    float acc = 0.f;
    if (nM > 0) {
#pragma unroll
      for (int j = 0; j < 12; ++j)
        acc += sb[d0 + j] * pwl[j] + cb[d0 + j] * wfl[j];
    } else {
#pragma unroll
      for (int j = 0; j < 12; ++j)
        acc += sb[d0 + j] * pwl[j];
    }
#pragma unroll
    for (int m = 1; m < 64; m <<= 1) acc += __shfl_xor(acc, m, 64);
    if (lane == 0) {
      float r = acc * (1.f / 23.f) + pb[l];
      if (nM > 0) r += (float)nM * boutdot[l] * (1.f / 23.f);
      out[(size_t)b * LL + l] = r;
    }
  }
}

extern "C" void kernel_launch(void* const* d_in, const int* in_sizes, int n_in,
                              void* d_out, int out_size, void* d_ws, size_t ws_size,
                              hipStream_t stream) {
  const float* cls  = (const float*)d_in[0];
  const int*   exm  = (const int*)d_in[1];
  const float* mt   = (const float*)d_in[2];
  const float* inw  = (const float*)d_in[3];
  const float* inb  = (const float*)d_in[4];
  const float* outw = (const float*)d_in[5];
  const float* outb = (const float*)d_in[6];
  const float* pw   = (const float*)d_in[7];
  const float* pb   = (const float*)d_in[8];
  float* out = (float*)d_out;

  char* ws = (char*)d_ws;
  size_t off = 0;
  auto alloc = [&](size_t bytes) {
    size_t cur = (off + 255) & ~(size_t)255;
    off = cur + bytes;
    return ws + cur;
  };
  int*   ex_off  = (int*)alloc((BB + 1) * sizeof(int));
  float* qmf     = (float*)alloc((size_t)SS * DD * 4);
  u16*   Bcomb   = (u16*)alloc((size_t)NN * DD * 2);
  float* biasc   = (float*)alloc((size_t)NN * 4);
  float* Wfold   = (float*)alloc((size_t)LL * DD * 4);
  float* boutdot = (float*)alloc((size_t)LL * 4);
  float* logits0 = (float*)alloc((size_t)LL * 4);
  float* mtm     = (float*)alloc((size_t)DD * 4);
  float* doc_acc = (float*)alloc((size_t)BB * DD * 4);
  float* ctxsum  = (float*)alloc((size_t)BB * DD * 4);
  u16*   Xex     = (u16*)alloc((size_t)NCAP * DD * 2);
  u16*   VS      = (u16*)alloc((size_t)NCAP * NN * 2);

  scan_kernel<<<1, 1024, 0, stream>>>(exm, ex_off);
  cast_bf16_kernel<<<(DD * DD / 8 + 255) / 256, 256, 0, stream>>>(inw + (size_t)2 * DD * DD, Bcomb, DD * DD);
  qmiss_kernel<<<SS * 3, 256, 0, stream>>>(mt, inw, inb, qmf);
  prepb_kernel<<<4, 256, 0, stream>>>(inb, biasc);
  gk_kernel<<<dim3(3, SS * HH), 256, 0, stream>>>(qmf, inw, inb, Bcomb, biasc);
  mtmean_kernel<<<1, DD, 0, stream>>>(mt, mtm);
  wfold_kernel<<<dim3(3, LL), 256, 0, stream>>>(pw, outw, outb, pb, mtm, Wfold, boutdot, logits0);
  gather_kernel<<<BB, 256, 0, stream>>>(cls, exm, ex_off, Xex, doc_acc);
  gemm_bt_kernel<<<dim3(NN / 128, MTILES), 256, 0, stream>>>(Xex, Bcomb, biasc, VS, ex_off + BB, NN);
  attn3_kernel<<<BB, 256, 0, stream>>>(VS, exm, ex_off, ctxsum);
  final2_kernel<<<BB, 256, 0, stream>>>(doc_acc, ctxsum, ex_off, pw, pb, Wfold, boutdot, logits0, out);
}

// Round 4
// 390.797 us; speedup vs baseline: 1.4398x; 1.1573x over previous
//
#include <hip/hip_runtime.h>
#include <hip/hip_bf16.h>

// ContextAwareContrastiveEmbeddingGenerator — MI355X (round 4).
// R4: launch consolidation 11 -> 4 (prep1, prep2+gather, GEMM, attn+final),
// ctxsum global round-trip eliminated (fused into attn_final), gather writes
// vectorized (float4 read / short4 write). GEMM left unchanged (known-good).

typedef unsigned short u16;
typedef unsigned int u32;
typedef __attribute__((ext_vector_type(8))) short sh8;    // 8 x bf16
typedef __attribute__((ext_vector_type(4))) float f32x4;  // MFMA acc

#define BB 2048
#define SS 23
#define DD 768
#define HH 8
#define HDIM 96
#define LL 50
#define NN 1024         // fused GEMM N: [0,768)=v, [768,952)=scores, rest pad
#define NCAP 26624      // 208*128 row cap (23552 expected, +28 sigma)
#define MTILES 208

__device__ __forceinline__ u16 f2bf(float f) {
  u32 u = __float_as_uint(f);
  u32 r = (u + 0x7fffu + ((u >> 16) & 1u)) >> 16;   // RNE
  return (u16)r;
}
__device__ __forceinline__ float bf2f(u16 h) {
  return __uint_as_float(((u32)h) << 16);
}

__device__ __forceinline__ void gld16(const void* g, void* l) {
  __builtin_amdgcn_global_load_lds((const __attribute__((address_space(1))) void*)g,
                                   (__attribute__((address_space(3))) void*)l, 16, 0, 0);
}

// ---------------- prep1: scan | Wv cast | qmiss | bias init (role by blockIdx) ----------------
__global__ __launch_bounds__(256) void prep1_kernel(const int* __restrict__ exist,
                                                    const float* __restrict__ inw,
                                                    const float* __restrict__ inb,
                                                    const float* __restrict__ mt,
                                                    int* __restrict__ ex_off,
                                                    u16* __restrict__ Bcomb,
                                                    float* __restrict__ biasc,
                                                    float* __restrict__ qmf) {
  const int idx = blockIdx.x;
  const int t = threadIdx.x;
  if (idx == 0) {
    // prefix scan of per-batch existing counts; thread t owns batches 8t..8t+7
    __shared__ int wtot[4];
    int c[8];
    int tot = 0;
    for (int j = 0; j < 8; ++j) {
      const int b = t * 8 + j;
      int cc = 0;
      for (int s = 0; s < SS; ++s) cc += (exist[b * SS + s] != 0);
      tot += cc;
      c[j] = tot;                      // thread-local inclusive
    }
    const int lane = t & 63, w = t >> 6;
    int v = tot;
    for (int off = 1; off < 64; off <<= 1) {
      int n = __shfl_up(v, off, 64);
      if (lane >= off) v += n;
    }
    if (lane == 63) wtot[w] = v;
    __syncthreads();
    int wbase = 0;
    for (int i = 0; i < w; ++i) wbase += wtot[i];
    const int excl = wbase + v - tot;  // exclusive prefix for this thread
    for (int j = 0; j < 8; ++j) ex_off[t * 8 + j + 1] = excl + c[j];
    if (t == 0) ex_off[0] = 0;
  } else if (idx < 289) {
    // cast Wv (in_proj_w rows [1536,2304)) -> Bcomb rows [0,768)
    const int i = ((idx - 1) * 256 + t) * 8;
    if (i < DD * DD) {
      const float* src = inw + (size_t)2 * DD * DD;
      float4 a = *(const float4*)(src + i);
      float4 b = *(const float4*)(src + i + 4);
      uint4 o;
      o.x = (u32)f2bf(a.x) | ((u32)f2bf(a.y) << 16);
      o.y = (u32)f2bf(a.z) | ((u32)f2bf(a.w) << 16);
      o.z = (u32)f2bf(b.x) | ((u32)f2bf(b.y) << 16);
      o.w = (u32)f2bf(b.z) | ((u32)f2bf(b.w) << 16);
      *(uint4*)((u16*)Bcomb + i) = o;
    }
  } else if (idx < 358) {
    // qmf[s][o] = (mt[s].Wq[o] + bq[o]) / sqrt(96)
    const int q69 = idx - 289;
    const int s = q69 / 3;
    const int o = (q69 % 3) * 256 + t;
    const float* mrow = mt + s * DD;
    const float* wrow = inw + (size_t)o * DD;
    float acc = 0.f;
    for (int d = 0; d < DD; d += 4) {
      float4 a = *(const float4*)(mrow + d);
      float4 b = *(const float4*)(wrow + d);
      acc += a.x * b.x + a.y * b.y + a.z * b.z + a.w * b.w;
    }
    qmf[s * DD + o] = (acc + inb[o]) * 0.10206207261596575f;
  } else {
    // biasc[0:768)=v-bias, rest 0 (score part overwritten by prep2)
    for (int i = t; i < NN; i += 256) biasc[i] = (i < DD) ? inb[1536 + i] : 0.f;
  }
}

// ---------------- prep2: g-rows | Wfold/boutdot/logits0 | gather (role by blockIdx) ----------------
__global__ __launch_bounds__(256) void prep2_kernel(const float* __restrict__ qmf,
                                                    const float* __restrict__ inw,
                                                    const float* __restrict__ inb,
                                                    const float* __restrict__ pw,
                                                    const float* __restrict__ pb,
                                                    const float* __restrict__ outw,
                                                    const float* __restrict__ outb,
                                                    const float* __restrict__ mt,
                                                    const float* __restrict__ cls,
                                                    const int* __restrict__ exist,
                                                    const int* __restrict__ ex_off,
                                                    u16* __restrict__ Bcomb,
                                                    float* __restrict__ biasc,
                                                    float* __restrict__ Wfold,
                                                    float* __restrict__ boutdot,
                                                    float* __restrict__ logits0,
                                                    u16* __restrict__ Xex,
                                                    float* __restrict__ doc_acc) {
  const int idx = blockIdx.x;
  const int t = threadIdx.x;
  __shared__ float red[2][256];
  __shared__ int exl[SS];
  __shared__ int nE_s;
  if (idx < 552) {
    // Bcomb score row: g[r][Dc] = sum_d q[s,h,d] * Wk[h*96+d][Dc]
    const int r = idx / 3, chunk = idx - r * 3;
    const int s = r >> 3, h = r & 7;
    const int Dc = chunk * 256 + t;
    const float* q = qmf + s * DD + h * HDIM;
    const float* wk = inw + (size_t)(DD + h * HDIM) * DD + Dc;
    float acc = 0.f;
    for (int d = 0; d < HDIM; ++d)
      acc += q[d] * wk[(size_t)d * DD];
    Bcomb[(size_t)(DD + r) * DD + Dc] = f2bf(acc);
    if (chunk == 0 && t == 0) {
      float bb = 0.f;
      const float* bk = inb + DD + h * HDIM;
      for (int d = 0; d < HDIM; ++d) bb += q[d] * bk[d];
      biasc[DD + r] = bb;
    }
  } else if (idx < 702) {
    // Wfold[l] = pw[l] @ outw; boutdot[l] = pw[l].outb; logits0[l] = pw[l].mtmean + pb[l]
    const int idx2 = idx - 552;
    const int l = idx2 / 3, chunk = idx2 - l * 3;
    const int din = chunk * 256 + t;
    float acc = 0.f;
    for (int dout = 0; dout < DD; ++dout)
      acc += pw[(size_t)l * DD + dout] * outw[(size_t)dout * DD + din];
    Wfold[(size_t)l * DD + din] = acc;
    if (chunk == 0) {
      float pbd = 0.f, plz = 0.f;
      for (int d = t; d < DD; d += 256) {
        const float pv = pw[(size_t)l * DD + d];
        pbd += pv * outb[d];
        float ms = 0.f;
        for (int s = 0; s < SS; ++s) ms += mt[s * DD + d];
        plz += pv * ms;
      }
      red[0][t] = pbd; red[1][t] = plz;
      __syncthreads();
      for (int s = 128; s > 0; s >>= 1) {
        if (t < s) { red[0][t] += red[0][t + s]; red[1][t] += red[1][t + s]; }
        __syncthreads();
      }
      if (t == 0) { boutdot[l] = red[0][0]; logits0[l] = red[1][0] * (1.f / 23.f) + pb[l]; }
    }
  } else {
    // gather batch b: existing cls rows -> bf16 Xex (compacted) + fp32 row sum
    const int b = idx - 702;
    if (t == 0) {
      int n = 0;
      for (int s = 0; s < SS; ++s) if (exist[b * SS + s]) exl[n++] = s;
      nE_s = n;
    }
    __syncthreads();
    const int nE = nE_s;
    const int e0 = ex_off[b];
    if (t < 192) {
      const int d0 = t * 4;
      float a0 = 0.f, a1 = 0.f, a2 = 0.f, a3 = 0.f;
      for (int i = 0; i < nE; ++i) {
        const float* row = cls + (size_t)(b * SS + exl[i]) * DD + d0;
        float4 v = *(const float4*)row;
        a0 += v.x; a1 += v.y; a2 += v.z; a3 += v.w;
        if (e0 + i < NCAP) {
          ushort4 pk;
          pk.x = f2bf(v.x); pk.y = f2bf(v.y); pk.z = f2bf(v.z); pk.w = f2bf(v.w);
          *(ushort4*)(Xex + (size_t)(e0 + i) * DD + d0) = pk;
        }
      }
      float4 outv = {a0, a1, a2, a3};
      *(float4*)(doc_acc + (size_t)b * DD + d0) = outv;
    }
  }
}

// ---------------- GEMM: C[m,n] = sum_k A[m,k]*Bw[n,k] + bias[n]  (bf16->bf16) ----------------
// 128x128 tile, BK=64, 4 waves, 4x4 16x16x32 MFMA frags. Grid (N/128, MTILES).
__global__ __launch_bounds__(256, 2)
void gemm_bt_kernel(const u16* __restrict__ A, const u16* __restrict__ Bw,
                    const float* __restrict__ bias, u16* __restrict__ Cc,
                    const int* __restrict__ rows_ptr, int N) {
  constexpr int K = 768;
  __shared__ u16 lA[128 * 64];
  __shared__ u16 lB[128 * 64];
  const int m0 = blockIdx.y * 128;
  if (m0 >= rows_ptr[0]) return;
  const int n0 = blockIdx.x * 128;
  const int t = threadIdx.x;
  const int w = t >> 6, l = t & 63;
  const int wr = (w >> 1) * 64, wc = (w & 1) * 64;
  const int r16 = l & 15, kg = l >> 4;

  f32x4 acc[4][4] = {};

  const int srow = t >> 3;
  const int scol = (t & 7) * 8;
  const u16* gA = A + (size_t)(m0 + srow) * K + scol;
  const u16* gB = Bw + (size_t)(n0 + srow) * K + scol;
  u16* lAp = lA + t * 8;
  u16* lBp = lB + t * 8;

  for (int kt = 0; kt < K; kt += 64) {
#pragma unroll
    for (int i = 0; i < 4; ++i) {
      gld16(gA + (size_t)i * 32 * K + kt, lAp + i * 2048);
      gld16(gB + (size_t)i * 32 * K + kt, lBp + i * 2048);
    }
    __syncthreads();
#pragma unroll
    for (int kk = 0; kk < 2; ++kk) {
      sh8 af[4], bfr[4];
      const int kc = kk * 32 + kg * 8;
#pragma unroll
      for (int m = 0; m < 4; ++m) af[m] = *(const sh8*)(lA + (wr + m * 16 + r16) * 64 + kc);
#pragma unroll
      for (int n = 0; n < 4; ++n) bfr[n] = *(const sh8*)(lB + (wc + n * 16 + r16) * 64 + kc);
#pragma unroll
      for (int m = 0; m < 4; ++m)
#pragma unroll
        for (int n = 0; n < 4; ++n)
          acc[m][n] = __builtin_amdgcn_mfma_f32_16x16x32_bf16(af[m], bfr[n], acc[m][n], 0, 0, 0);
    }
    __syncthreads();
  }

#pragma unroll
  for (int m = 0; m < 4; ++m) {
    const int row0 = m0 + wr + m * 16 + kg * 4;
#pragma unroll
    for (int n = 0; n < 4; ++n) {
      const int col = n0 + wc + n * 16 + r16;
      const float bv = bias[col];
#pragma unroll
      for (int j = 0; j < 4; ++j)
        Cc[(size_t)(row0 + j) * N + col] = f2bf(acc[m][n][j] + bv);
    }
  }
}

// ---------------- attn + final: softmax + psum + PV + logits, one block per batch ----------------
__global__ __launch_bounds__(256) void attn_final_kernel(const u16* __restrict__ VS,
                                                         const int* __restrict__ exist,
                                                         const int* __restrict__ ex_off,
                                                         const float* __restrict__ doc_acc,
                                                         const float* __restrict__ pw,
                                                         const float* __restrict__ pb,
                                                         const float* __restrict__ Wfold,
                                                         const float* __restrict__ boutdot,
                                                         const float* __restrict__ logits0,
                                                         float* __restrict__ out) {
  const int b = blockIdx.x, t = threadIdx.x;
  __shared__ float sc[SS * HH][25];   // [i*8+h][e], stride 25 (coprime 32)
  __shared__ float psum[HH][25];
  __shared__ float ctxL[DD];
  __shared__ int mil[SS], cnts[2];
  if (t == 0) {
    int ne = 0, nm = 0;
    for (int s = 0; s < SS; ++s) {
      if (exist[b * SS + s]) ne++; else mil[nm++] = s;
    }
    cnts[0] = ne; cnts[1] = nm;
  }
  __syncthreads();
  const int nE = cnts[0], nM = cnts[1];
  if (nE == 0) {
    if (t < LL) out[(size_t)b * LL + t] = logits0[t];
    return;
  }
  const size_t e0 = (size_t)ex_off[b];

  if (nM > 0) {
    // phase 1: score slice -> sc
    const int ee = t & 31, ig = t >> 5;
    for (int i0 = 0; i0 < nM; i0 += 8) {
      const int i = i0 + ig;
      if (ee < nE && i < nM) {
        sh8 v = *(const sh8*)(VS + (e0 + ee) * NN + DD + mil[i] * 8);
#pragma unroll
        for (int h = 0; h < HH; ++h) sc[i * HH + h][ee] = bf2f((u16)v[h]);
      }
    }
    __syncthreads();

    // phase 2a: softmax over e per row
    if (t < nM * HH) {
      float* row = sc[t];
      float mx = row[0];
      for (int e = 1; e < nE; ++e) mx = fmaxf(mx, row[e]);
      float sum = 0.f;
      for (int e = 0; e < nE; ++e) { float p = __expf(row[e] - mx); row[e] = p; sum += p; }
      float inv = 1.f / sum;
      for (int e = 0; e < nE; ++e) row[e] *= inv;
    }
    __syncthreads();

    // phase 2b: psum[h][e] = sum_i p[i*8+h][e]
    {
      const int h = t >> 5, e2 = t & 31;
      if (e2 < nE) {
        float a = 0.f;
        for (int i = 0; i < nM; ++i) a += sc[i * HH + h][e2];
        psum[h][e2] = a;
      }
    }
    __syncthreads();

    // phase 3: ctxL[d] = sum_e psum[h(d)][e] * v[e][d]
    for (int d = t; d < DD; d += 256) {
      const int h = d / HDIM;
      float acc = 0.f;
      for (int e = 0; e < nE; ++e)
        acc += psum[h][e] * bf2f(VS[(e0 + e) * NN + d]);
      ctxL[d] = acc;
    }
    __syncthreads();
  }

  // logits: wave w owns l = w, w+4, ...; lanes split d into 12-chunks
  const int w = t >> 6, lane = t & 63;
  const int d0 = lane * 12;
  const float* db = doc_acc + (size_t)b * DD + d0;
  float docv[12];
  *(float4*)(docv)     = *(const float4*)(db);
  *(float4*)(docv + 4) = *(const float4*)(db + 4);
  *(float4*)(docv + 8) = *(const float4*)(db + 8);
  float ctxv[12];
  if (nM > 0) {
#pragma unroll
    for (int j = 0; j < 12; ++j) ctxv[j] = ctxL[d0 + j];
  }
  for (int l = w; l < LL; l += 4) {
    const float* pwl = pw + (size_t)l * DD + d0;
    float acc = 0.f;
    if (nM > 0) {
      const float* wfl = Wfold + (size_t)l * DD + d0;
#pragma unroll
      for (int j = 0; j < 12; ++j) acc += docv[j] * pwl[j] + ctxv[j] * wfl[j];
    } else {
#pragma unroll
      for (int j = 0; j < 12; ++j) acc += docv[j] * pwl[j];
    }
#pragma unroll
    for (int m = 1; m < 64; m <<= 1) acc += __shfl_xor(acc, m, 64);
    if (lane == 0)
      out[(size_t)b * LL + l] = (acc + (float)nM * boutdot[l]) * (1.f / 23.f) + pb[l];
  }
}

extern "C" void kernel_launch(void* const* d_in, const int* in_sizes, int n_in,
                              void* d_out, int out_size, void* d_ws, size_t ws_size,
                              hipStream_t stream) {
  const float* cls  = (const float*)d_in[0];
  const int*   exm  = (const int*)d_in[1];
  const float* mt   = (const float*)d_in[2];
  const float* inw  = (const float*)d_in[3];
  const float* inb  = (const float*)d_in[4];
  const float* outw = (const float*)d_in[5];
  const float* outb = (const float*)d_in[6];
  const float* pw   = (const float*)d_in[7];
  const float* pb   = (const float*)d_in[8];
  float* out = (float*)d_out;

  char* ws = (char*)d_ws;
  size_t off = 0;
  auto alloc = [&](size_t bytes) {
    size_t cur = (off + 255) & ~(size_t)255;
    off = cur + bytes;
    return ws + cur;
  };
  int*   ex_off  = (int*)alloc((BB + 1) * sizeof(int));
  float* qmf     = (float*)alloc((size_t)SS * DD * 4);
  u16*   Bcomb   = (u16*)alloc((size_t)NN * DD * 2);
  float* biasc   = (float*)alloc((size_t)NN * 4);
  float* Wfold   = (float*)alloc((size_t)LL * DD * 4);
  float* boutdot = (float*)alloc((size_t)LL * 4);
  float* logits0 = (float*)alloc((size_t)LL * 4);
  float* doc_acc = (float*)alloc((size_t)BB * DD * 4);
  u16*   Xex     = (u16*)alloc((size_t)NCAP * DD * 2);
  u16*   VS      = (u16*)alloc((size_t)NCAP * NN * 2);

  prep1_kernel<<<359, 256, 0, stream>>>(exm, inw, inb, mt, ex_off, Bcomb, biasc, qmf);
  prep2_kernel<<<2750, 256, 0, stream>>>(qmf, inw, inb, pw, pb, outw, outb, mt, cls,
                                         exm, ex_off, Bcomb, biasc, Wfold, boutdot,
                                         logits0, Xex, doc_acc);
  gemm_bt_kernel<<<dim3(NN / 128, MTILES), 256, 0, stream>>>(Xex, Bcomb, biasc, VS,
                                                             ex_off + BB, NN);
  attn_final_kernel<<<BB, 256, 0, stream>>>(VS, exm, ex_off, doc_acc, pw, pb, Wfold,
                                            boutdot, logits0, out);
}

// Round 5
// 389.906 us; speedup vs baseline: 1.4430x; 1.0023x over previous
//
#include <hip/hip_runtime.h>
#include <hip/hip_bf16.h>

// ContextAwareContrastiveEmbeddingGenerator — MI355X (round 5).
// R5: prep2 de-serialized. Gather = 1 block/row via rowmap (built in prep1's
// scan block). doc_acc = block per (batch, d-chunk), same fp32 sum order as
// before. Wfold's 768-loop split into 4x192 chunks accumulated with fp32
// atomicAdd (zero-init in prep1). Roles ordered biggest-first. GEMM and
// attn_final unchanged (numerics stable; absmax must stay 2^-9).

typedef unsigned short u16;
typedef unsigned int u32;
typedef __attribute__((ext_vector_type(8))) short sh8;    // 8 x bf16
typedef __attribute__((ext_vector_type(4))) float f32x4;  // MFMA acc

#define BB 2048
#define SS 23
#define DD 768
#define HH 8
#define HDIM 96
#define LL 50
#define NN 1024         // fused GEMM N: [0,768)=v, [768,952)=scores, rest pad
#define NCAP 26624      // 208*128 row cap (23552 expected, +28 sigma)
#define MTILES 208

// prep2 role boundaries
#define G_GATHER 26624              // [0, 26624): per-row gather
#define G_DOC    (G_GATHER + 6144)  // doc_acc: 2048 batches x 3 chunks
#define G_GROW   (G_DOC + 552)      // g-rows: 184 x 3
#define G_WFOLD  (G_GROW + 600)     // Wfold: 50 x 3 x 4
#define G_LOG    (G_WFOLD + 50)     // boutdot/logits0

__device__ __forceinline__ u16 f2bf(float f) {
  u32 u = __float_as_uint(f);
  u32 r = (u + 0x7fffu + ((u >> 16) & 1u)) >> 16;   // RNE
  return (u16)r;
}
__device__ __forceinline__ float bf2f(u16 h) {
  return __uint_as_float(((u32)h) << 16);
}

__device__ __forceinline__ void gld16(const void* g, void* l) {
  __builtin_amdgcn_global_load_lds((const __attribute__((address_space(1))) void*)g,
                                   (__attribute__((address_space(3))) void*)l, 16, 0, 0);
}

// ---------------- prep1: scan+rowmap | Wv cast | qmiss | biasc | Wfold zero ----------------
__global__ __launch_bounds__(256) void prep1_kernel(const int* __restrict__ exist,
                                                    const float* __restrict__ inw,
                                                    const float* __restrict__ inb,
                                                    const float* __restrict__ mt,
                                                    int* __restrict__ ex_off,
                                                    int* __restrict__ rowmap,
                                                    u16* __restrict__ Bcomb,
                                                    float* __restrict__ biasc,
                                                    float* __restrict__ qmf,
                                                    float* __restrict__ Wfold) {
  const int idx = blockIdx.x;
  const int t = threadIdx.x;
  if (idx == 0) {
    // prefix scan of per-batch existing counts; thread t owns batches 8t..8t+7.
    __shared__ int wtot[4];
    int tot = 0;
    for (int j = 0; j < 8; ++j) {
      const int b = t * 8 + j;
      for (int s = 0; s < SS; ++s) tot += (exist[b * SS + s] != 0);
    }
    const int lane = t & 63, w = t >> 6;
    int v = tot;
    for (int off = 1; off < 64; off <<= 1) {
      int n = __shfl_up(v, off, 64);
      if (lane >= off) v += n;
    }
    if (lane == 63) wtot[w] = v;
    __syncthreads();
    int wbase = 0;
    for (int i = 0; i < w; ++i) wbase += wtot[i];
    int base = wbase + v - tot;        // exclusive prefix for this thread
    for (int j = 0; j < 8; ++j) {
      const int b = t * 8 + j;
      for (int s = 0; s < SS; ++s)
        if (exist[b * SS + s]) {
          if (base < NCAP) rowmap[base] = b * SS + s;
          ++base;
        }
      ex_off[b + 1] = base;
    }
    if (t == 0) ex_off[0] = 0;
  } else if (idx < 289) {
    // cast Wv (in_proj_w rows [1536,2304)) -> Bcomb rows [0,768)
    const int i = ((idx - 1) * 256 + t) * 8;
    const float* src = inw + (size_t)2 * DD * DD;
    float4 a = *(const float4*)(src + i);
    float4 b = *(const float4*)(src + i + 4);
    uint4 o;
    o.x = (u32)f2bf(a.x) | ((u32)f2bf(a.y) << 16);
    o.y = (u32)f2bf(a.z) | ((u32)f2bf(a.w) << 16);
    o.z = (u32)f2bf(b.x) | ((u32)f2bf(b.y) << 16);
    o.w = (u32)f2bf(b.z) | ((u32)f2bf(b.w) << 16);
    *(uint4*)((u16*)Bcomb + i) = o;
  } else if (idx < 358) {
    // qmf[s][o] = (mt[s].Wq[o] + bq[o]) / sqrt(96)
    const int q69 = idx - 289;
    const int s = q69 / 3;
    const int o = (q69 % 3) * 256 + t;
    const float* mrow = mt + s * DD;
    const float* wrow = inw + (size_t)o * DD;
    float acc = 0.f;
    for (int d = 0; d < DD; d += 4) {
      float4 a = *(const float4*)(mrow + d);
      float4 b = *(const float4*)(wrow + d);
      acc += a.x * b.x + a.y * b.y + a.z * b.z + a.w * b.w;
    }
    qmf[s * DD + o] = (acc + inb[o]) * 0.10206207261596575f;
  } else if (idx == 358) {
    // biasc[0:768)=v-bias, rest 0 (score part overwritten by prep2)
    for (int i = t; i < NN; i += 256) biasc[i] = (i < DD) ? inb[1536 + i] : 0.f;
  } else {
    // zero Wfold (atomic-accumulated in prep2): 9600 float4s
    const int i4 = (idx - 359) * 256 + t;
    if (i4 < (LL * DD) / 4) {
      float4 z = {0.f, 0.f, 0.f, 0.f};
      *(float4*)(Wfold + i4 * 4) = z;
    }
  }
}

// ---------------- prep2: gather | doc_acc | g-rows | Wfold | logits0 ----------------
__global__ __launch_bounds__(256) void prep2_kernel(const float* __restrict__ qmf,
                                                    const float* __restrict__ inw,
                                                    const float* __restrict__ inb,
                                                    const float* __restrict__ pw,
                                                    const float* __restrict__ pb,
                                                    const float* __restrict__ outw,
                                                    const float* __restrict__ outb,
                                                    const float* __restrict__ mt,
                                                    const float* __restrict__ cls,
                                                    const int* __restrict__ exist,
                                                    const int* __restrict__ ex_off,
                                                    const int* __restrict__ rowmap,
                                                    u16* __restrict__ Bcomb,
                                                    float* __restrict__ biasc,
                                                    float* __restrict__ Wfold,
                                                    float* __restrict__ boutdot,
                                                    float* __restrict__ logits0,
                                                    u16* __restrict__ Xex,
                                                    float* __restrict__ doc_acc) {
  const int idx = blockIdx.x;
  const int t = threadIdx.x;
  if (idx < G_GATHER) {
    // one block per compacted row: cls[rowmap[r]] -> bf16 Xex[r]
    const int r = idx;
    if (r >= ex_off[BB]) return;
    const int m = rowmap[r];
    if (t < 192) {
      const int d0 = t * 4;
      float4 v = *(const float4*)(cls + (size_t)m * DD + d0);
      ushort4 pk;
      pk.x = f2bf(v.x); pk.y = f2bf(v.y); pk.z = f2bf(v.z); pk.w = f2bf(v.w);
      *(ushort4*)(Xex + (size_t)r * DD + d0) = pk;
    }
  } else if (idx < G_DOC) {
    // doc_acc[b][d] = sum over existing s of cls[b,s,d]  (ascending s, fp32)
    const int id = idx - G_GATHER;
    const int b = id / 3;
    const int d = (id % 3) * 256 + t;
    const float* cb = cls + (size_t)b * SS * DD + d;
    float acc = 0.f;
    for (int s = 0; s < SS; ++s)
      if (exist[b * SS + s]) acc += cb[(size_t)s * DD];
    doc_acc[(size_t)b * DD + d] = acc;
  } else if (idx < G_GROW) {
    // Bcomb score row: g[r][Dc] = sum_d q[s,h,d] * Wk[h*96+d][Dc]
    const int id = idx - G_DOC;
    const int r = id / 3, chunk = id - r * 3;
    const int s = r >> 3, h = r & 7;
    const int Dc = chunk * 256 + t;
    const float* q = qmf + s * DD + h * HDIM;
    const float* wk = inw + (size_t)(DD + h * HDIM) * DD + Dc;
    float acc = 0.f;
    for (int d = 0; d < HDIM; ++d)
      acc += q[d] * wk[(size_t)d * DD];
    Bcomb[(size_t)(DD + r) * DD + Dc] = f2bf(acc);
    if (chunk == 0 && t == 0) {
      float bb = 0.f;
      const float* bk = inb + DD + h * HDIM;
      for (int d = 0; d < HDIM; ++d) bb += q[d] * bk[d];
      biasc[DD + r] = bb;
    }
  } else if (idx < G_WFOLD) {
    // Wfold[l][din] += sum over dout-chunk of pw[l][dout]*outw[dout][din]
    const int id = idx - G_GROW;
    const int l = id / 12, rem = id % 12;
    const int din = (rem % 3) * 256 + t;
    const int dc0 = (rem / 3) * 192;
    const float* pwl = pw + (size_t)l * DD;
    const float* ow = outw + (size_t)dc0 * DD + din;
    float acc = 0.f;
#pragma unroll 8
    for (int j = 0; j < 192; ++j)
      acc += pwl[dc0 + j] * ow[(size_t)j * DD];
    atomicAdd(&Wfold[(size_t)l * DD + din], acc);
  } else {
    // boutdot[l] = pw[l].outb; logits0[l] = pw[l].mtmean + pb[l]
    __shared__ float red[2][256];
    const int l = idx - G_WFOLD;
    float pbd = 0.f, plz = 0.f;
    for (int d = t; d < DD; d += 256) {
      const float pv = pw[(size_t)l * DD + d];
      pbd += pv * outb[d];
      float ms = 0.f;
      for (int s = 0; s < SS; ++s) ms += mt[s * DD + d];
      plz += pv * ms;
    }
    red[0][t] = pbd; red[1][t] = plz;
    __syncthreads();
    for (int s = 128; s > 0; s >>= 1) {
      if (t < s) { red[0][t] += red[0][t + s]; red[1][t] += red[1][t + s]; }
      __syncthreads();
    }
    if (t == 0) { boutdot[l] = red[0][0]; logits0[l] = red[1][0] * (1.f / 23.f) + pb[l]; }
  }
}

// ---------------- GEMM: C[m,n] = sum_k A[m,k]*Bw[n,k] + bias[n]  (bf16->bf16) ----------------
// 128x128 tile, BK=64, 4 waves, 4x4 16x16x32 MFMA frags. Grid (N/128, MTILES).
__global__ __launch_bounds__(256, 2)
void gemm_bt_kernel(const u16* __restrict__ A, const u16* __restrict__ Bw,
                    const float* __restrict__ bias, u16* __restrict__ Cc,
                    const int* __restrict__ rows_ptr, int N) {
  constexpr int K = 768;
  __shared__ u16 lA[128 * 64];
  __shared__ u16 lB[128 * 64];
  const int m0 = blockIdx.y * 128;
  if (m0 >= rows_ptr[0]) return;
  const int n0 = blockIdx.x * 128;
  const int t = threadIdx.x;
  const int w = t >> 6, l = t & 63;
  const int wr = (w >> 1) * 64, wc = (w & 1) * 64;
  const int r16 = l & 15, kg = l >> 4;

  f32x4 acc[4][4] = {};

  const int srow = t >> 3;
  const int scol = (t & 7) * 8;
  const u16* gA = A + (size_t)(m0 + srow) * K + scol;
  const u16* gB = Bw + (size_t)(n0 + srow) * K + scol;
  u16* lAp = lA + t * 8;
  u16* lBp = lB + t * 8;

  for (int kt = 0; kt < K; kt += 64) {
#pragma unroll
    for (int i = 0; i < 4; ++i) {
      gld16(gA + (size_t)i * 32 * K + kt, lAp + i * 2048);
      gld16(gB + (size_t)i * 32 * K + kt, lBp + i * 2048);
    }
    __syncthreads();
#pragma unroll
    for (int kk = 0; kk < 2; ++kk) {
      sh8 af[4], bfr[4];
      const int kc = kk * 32 + kg * 8;
#pragma unroll
      for (int m = 0; m < 4; ++m) af[m] = *(const sh8*)(lA + (wr + m * 16 + r16) * 64 + kc);
#pragma unroll
      for (int n = 0; n < 4; ++n) bfr[n] = *(const sh8*)(lB + (wc + n * 16 + r16) * 64 + kc);
#pragma unroll
      for (int m = 0; m < 4; ++m)
#pragma unroll
        for (int n = 0; n < 4; ++n)
          acc[m][n] = __builtin_amdgcn_mfma_f32_16x16x32_bf16(af[m], bfr[n], acc[m][n], 0, 0, 0);
    }
    __syncthreads();
  }

#pragma unroll
  for (int m = 0; m < 4; ++m) {
    const int row0 = m0 + wr + m * 16 + kg * 4;
#pragma unroll
    for (int n = 0; n < 4; ++n) {
      const int col = n0 + wc + n * 16 + r16;
      const float bv = bias[col];
#pragma unroll
      for (int j = 0; j < 4; ++j)
        Cc[(size_t)(row0 + j) * N + col] = f2bf(acc[m][n][j] + bv);
    }
  }
}

// ---------------- attn + final: softmax + psum + PV + logits, one block per batch ----------------
__global__ __launch_bounds__(256) void attn_final_kernel(const u16* __restrict__ VS,
                                                         const int* __restrict__ exist,
                                                         const int* __restrict__ ex_off,
                                                         const float* __restrict__ doc_acc,
                                                         const float* __restrict__ pw,
                                                         const float* __restrict__ pb,
                                                         const float* __restrict__ Wfold,
                                                         const float* __restrict__ boutdot,
                                                         const float* __restrict__ logits0,
                                                         float* __restrict__ out) {
  const int b = blockIdx.x, t = threadIdx.x;
  __shared__ float sc[SS * HH][25];   // [i*8+h][e], stride 25 (coprime 32)
  __shared__ float psum[HH][25];
  __shared__ float ctxL[DD];
  __shared__ int mil[SS], cnts[2];
  if (t == 0) {
    int ne = 0, nm = 0;
    for (int s = 0; s < SS; ++s) {
      if (exist[b * SS + s]) ne++; else mil[nm++] = s;
    }
    cnts[0] = ne; cnts[1] = nm;
  }
  __syncthreads();
  const int nE = cnts[0], nM = cnts[1];
  if (nE == 0) {
    if (t < LL) out[(size_t)b * LL + t] = logits0[t];
    return;
  }
  const size_t e0 = (size_t)ex_off[b];

  if (nM > 0) {
    // phase 1: score slice -> sc
    const int ee = t & 31, ig = t >> 5;
    for (int i0 = 0; i0 < nM; i0 += 8) {
      const int i = i0 + ig;
      if (ee < nE && i < nM) {
        sh8 v = *(const sh8*)(VS + (e0 + ee) * NN + DD + mil[i] * 8);
#pragma unroll
        for (int h = 0; h < HH; ++h) sc[i * HH + h][ee] = bf2f((u16)v[h]);
      }
    }
    __syncthreads();

    // phase 2a: softmax over e per row
    if (t < nM * HH) {
      float* row = sc[t];
      float mx = row[0];
      for (int e = 1; e < nE; ++e) mx = fmaxf(mx, row[e]);
      float sum = 0.f;
      for (int e = 0; e < nE; ++e) { float p = __expf(row[e] - mx); row[e] = p; sum += p; }
      float inv = 1.f / sum;
      for (int e = 0; e < nE; ++e) row[e] *= inv;
    }
    __syncthreads();

    // phase 2b: psum[h][e] = sum_i p[i*8+h][e]
    {
      const int h = t >> 5, e2 = t & 31;
      if (e2 < nE) {
        float a = 0.f;
        for (int i = 0; i < nM; ++i) a += sc[i * HH + h][e2];
        psum[h][e2] = a;
      }
    }
    __syncthreads();

    // phase 3: ctxL[d] = sum_e psum[h(d)][e] * v[e][d]
    for (int d = t; d < DD; d += 256) {
      const int h = d / HDIM;
      float acc = 0.f;
      for (int e = 0; e < nE; ++e)
        acc += psum[h][e] * bf2f(VS[(e0 + e) * NN + d]);
      ctxL[d] = acc;
    }
    __syncthreads();
  }

  // logits: wave w owns l = w, w+4, ...; lanes split d into 12-chunks
  const int w = t >> 6, lane = t & 63;
  const int d0 = lane * 12;
  const float* db = doc_acc + (size_t)b * DD + d0;
  float docv[12];
  *(float4*)(docv)     = *(const float4*)(db);
  *(float4*)(docv + 4) = *(const float4*)(db + 4);
  *(float4*)(docv + 8) = *(const float4*)(db + 8);
  float ctxv[12];
  if (nM > 0) {
#pragma unroll
    for (int j = 0; j < 12; ++j) ctxv[j] = ctxL[d0 + j];
  }
  for (int l = w; l < LL; l += 4) {
    const float* pwl = pw + (size_t)l * DD + d0;
    float acc = 0.f;
    if (nM > 0) {
      const float* wfl = Wfold + (size_t)l * DD + d0;
#pragma unroll
      for (int j = 0; j < 12; ++j) acc += docv[j] * pwl[j] + ctxv[j] * wfl[j];
    } else {
#pragma unroll
      for (int j = 0; j < 12; ++j) acc += docv[j] * pwl[j];
    }
#pragma unroll
    for (int m = 1; m < 64; m <<= 1) acc += __shfl_xor(acc, m, 64);
    if (lane == 0)
      out[(size_t)b * LL + l] = (acc + (float)nM * boutdot[l]) * (1.f / 23.f) + pb[l];
  }
}

extern "C" void kernel_launch(void* const* d_in, const int* in_sizes, int n_in,
                              void* d_out, int out_size, void* d_ws, size_t ws_size,
                              hipStream_t stream) {
  const float* cls  = (const float*)d_in[0];
  const int*   exm  = (const int*)d_in[1];
  const float* mt   = (const float*)d_in[2];
  const float* inw  = (const float*)d_in[3];
  const float* inb  = (const float*)d_in[4];
  const float* outw = (const float*)d_in[5];
  const float* outb = (const float*)d_in[6];
  const float* pw   = (const float*)d_in[7];
  const float* pb   = (const float*)d_in[8];
  float* out = (float*)d_out;

  char* ws = (char*)d_ws;
  size_t off = 0;
  auto alloc = [&](size_t bytes) {
    size_t cur = (off + 255) & ~(size_t)255;
    off = cur + bytes;
    return ws + cur;
  };
  int*   ex_off  = (int*)alloc((BB + 1) * sizeof(int));
  int*   rowmap  = (int*)alloc((size_t)NCAP * sizeof(int));
  float* qmf     = (float*)alloc((size_t)SS * DD * 4);
  u16*   Bcomb   = (u16*)alloc((size_t)NN * DD * 2);
  float* biasc   = (float*)alloc((size_t)NN * 4);
  float* Wfold   = (float*)alloc((size_t)LL * DD * 4);
  float* boutdot = (float*)alloc((size_t)LL * 4);
  float* logits0 = (float*)alloc((size_t)LL * 4);
  float* doc_acc = (float*)alloc((size_t)BB * DD * 4);
  u16*   Xex     = (u16*)alloc((size_t)NCAP * DD * 2);
  u16*   VS      = (u16*)alloc((size_t)NCAP * NN * 2);

  prep1_kernel<<<397, 256, 0, stream>>>(exm, inw, inb, mt, ex_off, rowmap, Bcomb,
                                        biasc, qmf, Wfold);
  prep2_kernel<<<G_LOG, 256, 0, stream>>>(qmf, inw, inb, pw, pb, outw, outb, mt, cls,
                                          exm, ex_off, rowmap, Bcomb, biasc, Wfold,
                                          boutdot, logits0, Xex, doc_acc);
  gemm_bt_kernel<<<dim3(NN / 128, MTILES), 256, 0, stream>>>(Xex, Bcomb, biasc, VS,
                                                             ex_off + BB, NN);
  attn_final_kernel<<<BB, 256, 0, stream>>>(VS, exm, ex_off, doc_acc, pw, pb, Wfold,
                                            boutdot, logits0, out);
}

// Round 6
// 342.488 us; speedup vs baseline: 1.6428x; 1.1385x over previous
//
#include <hip/hip_runtime.h>
#include <hip/hip_bf16.h>

// ContextAwareContrastiveEmbeddingGenerator — MI355X (round 6).
// R6: (1) GEMM 1D grid with bijective XCD-chunked mapping — old grid(8,208)
// put N-tile index on XCD (id%8 = x), so every XCD streamed all of A (~8x36MB
// HBM). New mapping gives each XCD 26 M-tiles, 8 N-tiles back-to-back.
// (2) prep2: gather + doc_acc fused into one per-batch role (cls read once,
// same ascending-s fp32 order -> bit-identical), long-chain roles dispatched
// first (Wfold, g-rows), gather after, logits last.

typedef unsigned short u16;
typedef unsigned int u32;
typedef __attribute__((ext_vector_type(8))) short sh8;    // 8 x bf16
typedef __attribute__((ext_vector_type(4))) float f32x4;  // MFMA acc

#define BB 2048
#define SS 23
#define DD 768
#define HH 8
#define HDIM 96
#define LL 50
#define NN 1024         // fused GEMM N: [0,768)=v, [768,952)=scores, rest pad
#define NCAP 26624      // 208*128 row cap (23552 expected, +28 sigma)
#define MTILES 208

// prep2 role boundaries (long serial chains first)
#define G_WFOLD  600                 // [0,600): Wfold 50 x 3 x 4
#define G_GROW   (G_WFOLD + 552)     // g-rows: 184 x 3
#define G_GATHER (G_GROW + 2048)     // fused gather+doc: 1/batch
#define G_LOG    (G_GATHER + 50)     // boutdot/logits0

__device__ __forceinline__ u16 f2bf(float f) {
  u32 u = __float_as_uint(f);
  u32 r = (u + 0x7fffu + ((u >> 16) & 1u)) >> 16;   // RNE
  return (u16)r;
}
__device__ __forceinline__ float bf2f(u16 h) {
  return __uint_as_float(((u32)h) << 16);
}

__device__ __forceinline__ void gld16(const void* g, void* l) {
  __builtin_amdgcn_global_load_lds((const __attribute__((address_space(1))) void*)g,
                                   (__attribute__((address_space(3))) void*)l, 16, 0, 0);
}

// ---------------- prep1: scan | Wv cast | qmiss | biasc | Wfold zero ----------------
__global__ __launch_bounds__(256) void prep1_kernel(const int* __restrict__ exist,
                                                    const float* __restrict__ inw,
                                                    const float* __restrict__ inb,
                                                    const float* __restrict__ mt,
                                                    int* __restrict__ ex_off,
                                                    u16* __restrict__ Bcomb,
                                                    float* __restrict__ biasc,
                                                    float* __restrict__ qmf,
                                                    float* __restrict__ Wfold) {
  const int idx = blockIdx.x;
  const int t = threadIdx.x;
  if (idx == 0) {
    // prefix scan of per-batch existing counts; thread t owns batches 8t..8t+7.
    __shared__ int wtot[4];
    int c[8];
    int tot = 0;
    for (int j = 0; j < 8; ++j) {
      const int b = t * 8 + j;
      int cc = 0;
      for (int s = 0; s < SS; ++s) cc += (exist[b * SS + s] != 0);
      tot += cc;
      c[j] = tot;
    }
    const int lane = t & 63, w = t >> 6;
    int v = tot;
    for (int off = 1; off < 64; off <<= 1) {
      int n = __shfl_up(v, off, 64);
      if (lane >= off) v += n;
    }
    if (lane == 63) wtot[w] = v;
    __syncthreads();
    int wbase = 0;
    for (int i = 0; i < w; ++i) wbase += wtot[i];
    const int excl = wbase + v - tot;
    for (int j = 0; j < 8; ++j) ex_off[t * 8 + j + 1] = excl + c[j];
    if (t == 0) ex_off[0] = 0;
  } else if (idx < 289) {
    // cast Wv (in_proj_w rows [1536,2304)) -> Bcomb rows [0,768)
    const int i = ((idx - 1) * 256 + t) * 8;
    const float* src = inw + (size_t)2 * DD * DD;
    float4 a = *(const float4*)(src + i);
    float4 b = *(const float4*)(src + i + 4);
    uint4 o;
    o.x = (u32)f2bf(a.x) | ((u32)f2bf(a.y) << 16);
    o.y = (u32)f2bf(a.z) | ((u32)f2bf(a.w) << 16);
    o.z = (u32)f2bf(b.x) | ((u32)f2bf(b.y) << 16);
    o.w = (u32)f2bf(b.z) | ((u32)f2bf(b.w) << 16);
    *(uint4*)((u16*)Bcomb + i) = o;
  } else if (idx < 358) {
    // qmf[s][o] = (mt[s].Wq[o] + bq[o]) / sqrt(96)
    const int q69 = idx - 289;
    const int s = q69 / 3;
    const int o = (q69 % 3) * 256 + t;
    const float* mrow = mt + s * DD;
    const float* wrow = inw + (size_t)o * DD;
    float acc = 0.f;
    for (int d = 0; d < DD; d += 4) {
      float4 a = *(const float4*)(mrow + d);
      float4 b = *(const float4*)(wrow + d);
      acc += a.x * b.x + a.y * b.y + a.z * b.z + a.w * b.w;
    }
    qmf[s * DD + o] = (acc + inb[o]) * 0.10206207261596575f;
  } else if (idx == 358) {
    // biasc[0:768)=v-bias, rest 0 (score part overwritten by prep2)
    for (int i = t; i < NN; i += 256) biasc[i] = (i < DD) ? inb[1536 + i] : 0.f;
  } else {
    // zero Wfold (atomic-accumulated in prep2): 9600 float4s
    const int i4 = (idx - 359) * 256 + t;
    if (i4 < (LL * DD) / 4) {
      float4 z = {0.f, 0.f, 0.f, 0.f};
      *(float4*)(Wfold + i4 * 4) = z;
    }
  }
}

// ---------------- prep2: Wfold | g-rows | fused gather+doc | logits0 ----------------
__global__ __launch_bounds__(256) void prep2_kernel(const float* __restrict__ qmf,
                                                    const float* __restrict__ inw,
                                                    const float* __restrict__ inb,
                                                    const float* __restrict__ pw,
                                                    const float* __restrict__ pb,
                                                    const float* __restrict__ outw,
                                                    const float* __restrict__ outb,
                                                    const float* __restrict__ mt,
                                                    const float* __restrict__ cls,
                                                    const int* __restrict__ exist,
                                                    const int* __restrict__ ex_off,
                                                    u16* __restrict__ Bcomb,
                                                    float* __restrict__ biasc,
                                                    float* __restrict__ Wfold,
                                                    float* __restrict__ boutdot,
                                                    float* __restrict__ logits0,
                                                    u16* __restrict__ Xex,
                                                    float* __restrict__ doc_acc) {
  const int idx = blockIdx.x;
  const int t = threadIdx.x;
  if (idx < G_WFOLD) {
    // Wfold[l][din] += sum over dout-chunk of pw[l][dout]*outw[dout][din]
    const int l = idx / 12, rem = idx % 12;
    const int din = (rem % 3) * 256 + t;
    const int dc0 = (rem / 3) * 192;
    const float* pwl = pw + (size_t)l * DD;
    const float* ow = outw + (size_t)dc0 * DD + din;
    float acc = 0.f;
#pragma unroll 8
    for (int j = 0; j < 192; ++j)
      acc += pwl[dc0 + j] * ow[(size_t)j * DD];
    atomicAdd(&Wfold[(size_t)l * DD + din], acc);
  } else if (idx < G_GROW) {
    // Bcomb score row: g[r][Dc] = sum_d q[s,h,d] * Wk[h*96+d][Dc]
    const int id = idx - G_WFOLD;
    const int r = id / 3, chunk = id - r * 3;
    const int s = r >> 3, h = r & 7;
    const int Dc = chunk * 256 + t;
    const float* q = qmf + s * DD + h * HDIM;
    const float* wk = inw + (size_t)(DD + h * HDIM) * DD + Dc;
    float acc = 0.f;
    for (int d = 0; d < HDIM; ++d)
      acc += q[d] * wk[(size_t)d * DD];
    Bcomb[(size_t)(DD + r) * DD + Dc] = f2bf(acc);
    if (chunk == 0 && t == 0) {
      float bb = 0.f;
      const float* bk = inb + DD + h * HDIM;
      for (int d = 0; d < HDIM; ++d) bb += q[d] * bk[d];
      biasc[DD + r] = bb;
    }
  } else if (idx < G_GATHER) {
    // fused per-batch gather + doc sum: cls read ONCE. Thread t owns d0=4t.
    const int b = idx - G_GROW;
    if (t < 192) {
      const int d0 = t * 4;
      int r = ex_off[b];
      float a0 = 0.f, a1 = 0.f, a2 = 0.f, a3 = 0.f;
      const float* cb = cls + (size_t)b * SS * DD + d0;
      for (int s = 0; s < SS; ++s) {
        if (exist[b * SS + s]) {
          float4 v = *(const float4*)(cb + (size_t)s * DD);
          a0 += v.x; a1 += v.y; a2 += v.z; a3 += v.w;
          if (r < NCAP) {
            ushort4 pk;
            pk.x = f2bf(v.x); pk.y = f2bf(v.y); pk.z = f2bf(v.z); pk.w = f2bf(v.w);
            *(ushort4*)(Xex + (size_t)r * DD + d0) = pk;
          }
          ++r;
        }
      }
      float4 outv = {a0, a1, a2, a3};
      *(float4*)(doc_acc + (size_t)b * DD + d0) = outv;
    }
  } else {
    // boutdot[l] = pw[l].outb; logits0[l] = pw[l].mtmean + pb[l]
    __shared__ float red[2][256];
    const int l = idx - G_GATHER;
    float pbd = 0.f, plz = 0.f;
    for (int d = t; d < DD; d += 256) {
      const float pv = pw[(size_t)l * DD + d];
      pbd += pv * outb[d];
      float ms = 0.f;
      for (int s = 0; s < SS; ++s) ms += mt[s * DD + d];
      plz += pv * ms;
    }
    red[0][t] = pbd; red[1][t] = plz;
    __syncthreads();
    for (int s = 128; s > 0; s >>= 1) {
      if (t < s) { red[0][t] += red[0][t + s]; red[1][t] += red[1][t + s]; }
      __syncthreads();
    }
    if (t == 0) { boutdot[l] = red[0][0]; logits0[l] = red[1][0] * (1.f / 23.f) + pb[l]; }
  }
}

// ---------------- GEMM: C[m,n] = sum_k A[m,k]*Bw[n,k] + bias[n]  (bf16->bf16) ----------------
// 128x128 tile, BK=64, 4 waves, 4x4 16x16x32 MFMA frags. 1D grid, XCD-chunked:
// xcd = i&7 owns M-tiles {xcd+8k}; its 8 N-tiles of one M-tile run back-to-back
// so the A-tile is fetched into that XCD's L2 once; B (1.5MB) L2-resident.
__global__ __launch_bounds__(256, 2)
void gemm_bt_kernel(const u16* __restrict__ A, const u16* __restrict__ Bw,
                    const float* __restrict__ bias, u16* __restrict__ Cc,
                    const int* __restrict__ rows_ptr, int N) {
  constexpr int K = 768;
  __shared__ u16 lA[128 * 64];
  __shared__ u16 lB[128 * 64];
  const int i = blockIdx.x;
  const int xcd = i & 7;
  const int j = i >> 3;                       // 0..207
  const int m_tile = xcd + ((j >> 3) << 3);   // xcd + 8*(j/8)
  const int n_tile = j & 7;
  const int m0 = m_tile * 128;
  if (m0 >= rows_ptr[0]) return;
  const int n0 = n_tile * 128;
  const int t = threadIdx.x;
  const int w = t >> 6, l = t & 63;
  const int wr = (w >> 1) * 64, wc = (w & 1) * 64;
  const int r16 = l & 15, kg = l >> 4;

  f32x4 acc[4][4] = {};

  const int srow = t >> 3;
  const int scol = (t & 7) * 8;
  const u16* gA = A + (size_t)(m0 + srow) * K + scol;
  const u16* gB = Bw + (size_t)(n0 + srow) * K + scol;
  u16* lAp = lA + t * 8;
  u16* lBp = lB + t * 8;

  for (int kt = 0; kt < K; kt += 64) {
#pragma unroll
    for (int ii = 0; ii < 4; ++ii) {
      gld16(gA + (size_t)ii * 32 * K + kt, lAp + ii * 2048);
      gld16(gB + (size_t)ii * 32 * K + kt, lBp + ii * 2048);
    }
    __syncthreads();
#pragma unroll
    for (int kk = 0; kk < 2; ++kk) {
      sh8 af[4], bfr[4];
      const int kc = kk * 32 + kg * 8;
#pragma unroll
      for (int m = 0; m < 4; ++m) af[m] = *(const sh8*)(lA + (wr + m * 16 + r16) * 64 + kc);
#pragma unroll
      for (int n = 0; n < 4; ++n) bfr[n] = *(const sh8*)(lB + (wc + n * 16 + r16) * 64 + kc);
#pragma unroll
      for (int m = 0; m < 4; ++m)
#pragma unroll
        for (int n = 0; n < 4; ++n)
          acc[m][n] = __builtin_amdgcn_mfma_f32_16x16x32_bf16(af[m], bfr[n], acc[m][n], 0, 0, 0);
    }
    __syncthreads();
  }

#pragma unroll
  for (int m = 0; m < 4; ++m) {
    const int row0 = m0 + wr + m * 16 + kg * 4;
#pragma unroll
    for (int n = 0; n < 4; ++n) {
      const int col = n0 + wc + n * 16 + r16;
      const float bv = bias[col];
#pragma unroll
      for (int jj = 0; jj < 4; ++jj)
        Cc[(size_t)(row0 + jj) * N + col] = f2bf(acc[m][n][jj] + bv);
    }
  }
}

// ---------------- attn + final: softmax + psum + PV + logits, one block per batch ----------------
__global__ __launch_bounds__(256) void attn_final_kernel(const u16* __restrict__ VS,
                                                         const int* __restrict__ exist,
                                                         const int* __restrict__ ex_off,
                                                         const float* __restrict__ doc_acc,
                                                         const float* __restrict__ pw,
                                                         const float* __restrict__ pb,
                                                         const float* __restrict__ Wfold,
                                                         const float* __restrict__ boutdot,
                                                         const float* __restrict__ logits0,
                                                         float* __restrict__ out) {
  const int b = blockIdx.x, t = threadIdx.x;
  __shared__ float sc[SS * HH][25];   // [i*8+h][e], stride 25 (coprime 32)
  __shared__ float psum[HH][25];
  __shared__ float ctxL[DD];
  __shared__ int mil[SS], cnts[2];
  if (t == 0) {
    int ne = 0, nm = 0;
    for (int s = 0; s < SS; ++s) {
      if (exist[b * SS + s]) ne++; else mil[nm++] = s;
    }
    cnts[0] = ne; cnts[1] = nm;
  }
  __syncthreads();
  const int nE = cnts[0], nM = cnts[1];
  if (nE == 0) {
    if (t < LL) out[(size_t)b * LL + t] = logits0[t];
    return;
  }
  const size_t e0 = (size_t)ex_off[b];

  if (nM > 0) {
    // phase 1: score slice -> sc
    const int ee = t & 31, ig = t >> 5;
    for (int i0 = 0; i0 < nM; i0 += 8) {
      const int i = i0 + ig;
      if (ee < nE && i < nM) {
        sh8 v = *(const sh8*)(VS + (e0 + ee) * NN + DD + mil[i] * 8);
#pragma unroll
        for (int h = 0; h < HH; ++h) sc[i * HH + h][ee] = bf2f((u16)v[h]);
      }
    }
    __syncthreads();

    // phase 2a: softmax over e per row
    if (t < nM * HH) {
      float* row = sc[t];
      float mx = row[0];
      for (int e = 1; e < nE; ++e) mx = fmaxf(mx, row[e]);
      float sum = 0.f;
      for (int e = 0; e < nE; ++e) { float p = __expf(row[e] - mx); row[e] = p; sum += p; }
      float inv = 1.f / sum;
      for (int e = 0; e < nE; ++e) row[e] *= inv;
    }
    __syncthreads();

    // phase 2b: psum[h][e] = sum_i p[i*8+h][e]
    {
      const int h = t >> 5, e2 = t & 31;
      if (e2 < nE) {
        float a = 0.f;
        for (int i = 0; i < nM; ++i) a += sc[i * HH + h][e2];
        psum[h][e2] = a;
      }
    }
    __syncthreads();

    // phase 3: ctxL[d] = sum_e psum[h(d)][e] * v[e][d]
    for (int d = t; d < DD; d += 256) {
      const int h = d / HDIM;
      float acc = 0.f;
      for (int e = 0; e < nE; ++e)
        acc += psum[h][e] * bf2f(VS[(e0 + e) * NN + d]);
      ctxL[d] = acc;
    }
    __syncthreads();
  }

  // logits: wave w owns l = w, w+4, ...; lanes split d into 12-chunks
  const int w = t >> 6, lane = t & 63;
  const int d0 = lane * 12;
  const float* db = doc_acc + (size_t)b * DD + d0;
  float docv[12];
  *(float4*)(docv)     = *(const float4*)(db);
  *(float4*)(docv + 4) = *(const float4*)(db + 4);
  *(float4*)(docv + 8) = *(const float4*)(db + 8);
  float ctxv[12];
  if (nM > 0) {
#pragma unroll
    for (int j = 0; j < 12; ++j) ctxv[j] = ctxL[d0 + j];
  }
  for (int l = w; l < LL; l += 4) {
    const float* pwl = pw + (size_t)l * DD + d0;
    float acc = 0.f;
    if (nM > 0) {
      const float* wfl = Wfold + (size_t)l * DD + d0;
#pragma unroll
      for (int j = 0; j < 12; ++j) acc += docv[j] * pwl[j] + ctxv[j] * wfl[j];
    } else {
#pragma unroll
      for (int j = 0; j < 12; ++j) acc += docv[j] * pwl[j];
    }
#pragma unroll
    for (int m = 1; m < 64; m <<= 1) acc += __shfl_xor(acc, m, 64);
    if (lane == 0)
      out[(size_t)b * LL + l] = (acc + (float)nM * boutdot[l]) * (1.f / 23.f) + pb[l];
  }
}

extern "C" void kernel_launch(void* const* d_in, const int* in_sizes, int n_in,
                              void* d_out, int out_size, void* d_ws, size_t ws_size,
                              hipStream_t stream) {
  const float* cls  = (const float*)d_in[0];
  const int*   exm  = (const int*)d_in[1];
  const float* mt   = (const float*)d_in[2];
  const float* inw  = (const float*)d_in[3];
  const float* inb  = (const float*)d_in[4];
  const float* outw = (const float*)d_in[5];
  const float* outb = (const float*)d_in[6];
  const float* pw   = (const float*)d_in[7];
  const float* pb   = (const float*)d_in[8];
  float* out = (float*)d_out;

  char* ws = (char*)d_ws;
  size_t off = 0;
  auto alloc = [&](size_t bytes) {
    size_t cur = (off + 255) & ~(size_t)255;
    off = cur + bytes;
    return ws + cur;
  };
  int*   ex_off  = (int*)alloc((BB + 1) * sizeof(int));
  float* qmf     = (float*)alloc((size_t)SS * DD * 4);
  u16*   Bcomb   = (u16*)alloc((size_t)NN * DD * 2);
  float* biasc   = (float*)alloc((size_t)NN * 4);
  float* Wfold   = (float*)alloc((size_t)LL * DD * 4);
  float* boutdot = (float*)alloc((size_t)LL * 4);
  float* logits0 = (float*)alloc((size_t)LL * 4);
  float* doc_acc = (float*)alloc((size_t)BB * DD * 4);
  u16*   Xex     = (u16*)alloc((size_t)NCAP * DD * 2);
  u16*   VS      = (u16*)alloc((size_t)NCAP * NN * 2);

  prep1_kernel<<<397, 256, 0, stream>>>(exm, inw, inb, mt, ex_off, Bcomb, biasc,
                                        qmf, Wfold);
  prep2_kernel<<<G_LOG, 256, 0, stream>>>(qmf, inw, inb, pw, pb, outw, outb, mt, cls,
                                          exm, ex_off, Bcomb, biasc, Wfold,
                                          boutdot, logits0, Xex, doc_acc);
  gemm_bt_kernel<<<MTILES * (NN / 128), 256, 0, stream>>>(Xex, Bcomb, biasc, VS,
                                                          ex_off + BB, NN);
  attn_final_kernel<<<BB, 256, 0, stream>>>(VS, exm, ex_off, doc_acc, pw, pb, Wfold,
                                            boutdot, logits0, out);
}